// Round 1
// baseline (447.936 us; speedup 1.0000x reference)
//
#include <hip/hip_runtime.h>

typedef __bf16 bf16;
typedef __bf16 bf16x4 __attribute__((ext_vector_type(4)));
typedef __bf16 bf16x8 __attribute__((ext_vector_type(8)));
typedef float f32x4 __attribute__((ext_vector_type(4)));

#define B_SZ 32768
#define T_CAT 26
#define V_SZ 100000
#define E_SZ 128

__device__ __forceinline__ void gload_lds16(const void* g, void* l) {
    __builtin_amdgcn_global_load_lds(
        (const __attribute__((address_space(1))) void*)g,
        (__attribute__((address_space(3))) void*)l, 16, 0, 0);
}

// ---------------------------------------------------------------------------
// Weight convert: W (K x N fp32, row-major) -> Wt (N x Kp bf16, row-major),
// zero-padded for k in [K, Kp). Reads coalesced along n.
// ---------------------------------------------------------------------------
__global__ __launch_bounds__(256) void convw(const float* __restrict__ W,
                                             bf16* __restrict__ Wt,
                                             int K, int N, int Kp) {
    const int idx = blockIdx.x * 256 + threadIdx.x;
    if (idx >= Kp * N) return;
    const int k = idx / N;
    const int n = idx - k * N;
    const float v = (k < K) ? W[(long)k * N + n] : 0.0f;
    Wt[(long)n * Kp + k] = (bf16)v;
}

// numerical (B x 13 fp32) -> xpad (B x 64 bf16), cols 13..63 zero
__global__ __launch_bounds__(256) void make_xpad(const float* __restrict__ num,
                                                 bf16* __restrict__ xp) {
    const int idx = blockIdx.x * 256 + threadIdx.x;  // B*64 threads
    const int b = idx >> 6, c = idx & 63;
    xp[idx] = (bf16)((c < 13) ? num[(long)b * 13 + c] : 0.0f);
}

// ---------------------------------------------------------------------------
// GEMM: C[M,N] = act(A[M,K] @ Bt^T + bias), A bf16 row-major, Bt = W^T bf16
// (N x K row-major), fp32 accum, bf16 out. M%128==0, N%128==0, K%64==0.
// m97 structure: 128x128 tile, BK=64, 4 waves (2x2), global_load_lds staging.
// ---------------------------------------------------------------------------
template <int RELU>
__global__ __launch_bounds__(256) void gemm_bt(const bf16* __restrict__ A,
                                               const bf16* __restrict__ Bt,
                                               const float* __restrict__ bias,
                                               bf16* __restrict__ C,
                                               int M, int N, int K) {
    __shared__ __align__(16) bf16 As[128 * 64];
    __shared__ __align__(16) bf16 Bs[128 * 64];
    const int t = threadIdx.x;
    const int lane = t & 63;
    const int w = t >> 6;
    const int wm = w >> 1, wn = w & 1;
    const long row0 = (long)blockIdx.y * 128;
    const long col0 = (long)blockIdx.x * 128;

    // staging: thread t covers (per round q of 4): row q*32 + t/8, elem col (t&7)*8
    const int srow = t >> 3;
    const int scol = (t & 7) * 8;
    const bf16* Ag = A + (row0 + srow) * (long)K + scol;
    const bf16* Bg = Bt + (col0 + srow) * (long)K + scol;
    bf16* AsB = &As[w * 512];  // wave-uniform LDS base; HW adds lane*16B
    bf16* BsB = &Bs[w * 512];

    f32x4 acc[4][4] = {};

    for (int k0 = 0; k0 < K; k0 += 64) {
#pragma unroll
        for (int q = 0; q < 4; ++q) {
            gload_lds16(Ag + (long)q * 32 * K + k0, AsB + q * 2048);
            gload_lds16(Bg + (long)q * 32 * K + k0, BsB + q * 2048);
        }
        __syncthreads();
#pragma unroll
        for (int s = 0; s < 2; ++s) {
            bf16x8 af[4], bv[4];
#pragma unroll
            for (int i = 0; i < 4; ++i)
                af[i] = *(const bf16x8*)&As[(wm * 64 + i * 16 + (lane & 15)) * 64 +
                                            s * 32 + (lane >> 4) * 8];
#pragma unroll
            for (int j = 0; j < 4; ++j)
                bv[j] = *(const bf16x8*)&Bs[(wn * 64 + j * 16 + (lane & 15)) * 64 +
                                            s * 32 + (lane >> 4) * 8];
#pragma unroll
            for (int i = 0; i < 4; ++i)
#pragma unroll
                for (int j = 0; j < 4; ++j)
                    acc[i][j] = __builtin_amdgcn_mfma_f32_16x16x32_bf16(
                        af[i], bv[j], acc[i][j], 0, 0, 0);
        }
        __syncthreads();
    }

    // epilogue: D row = (lane>>4)*4 + reg, col = lane&15  [m89 layout]
    const int r4 = (lane >> 4) * 4;
    const int cn = lane & 15;
#pragma unroll
    for (int j = 0; j < 4; ++j) {
        const long col = col0 + wn * 64 + j * 16 + cn;
        const float bj = bias[col];
#pragma unroll
        for (int i = 0; i < 4; ++i) {
#pragma unroll
            for (int r = 0; r < 4; ++r) {
                const long row = row0 + wm * 64 + i * 16 + r4 + r;
                float v = acc[i][j][r] + bj;
                if (RELU) v = v > 0.0f ? v : 0.0f;
                C[row * (long)N + col] = (bf16)v;
            }
        }
    }
}

// ---------------------------------------------------------------------------
// Fused embedding gather + pairwise interaction + top_in assembly.
// 1 wave per sample, 4 samples per block.
// top_in row (512): [0,128) bottom_out, [128,479) pairs, [479,512) zeros.
// ---------------------------------------------------------------------------
__global__ __launch_bounds__(256) void interact_k(const float* __restrict__ emb,
                                                  const int* __restrict__ cat,
                                                  const bf16* __restrict__ bottom,
                                                  bf16* __restrict__ top_in) {
    __shared__ __align__(16) bf16 feats[4][32 * 128];
    __shared__ float gram[4][32 * 32];
    const int t = threadIdx.x;
    const int lane = t & 63;
    const int w = t >> 6;
    const long s = (long)blockIdx.x * 4 + w;

    // row 0 = bottom_out (already bf16)
    if (lane < 16)
        ((bf16x8*)&feats[w][0])[lane] = ((const bf16x8*)(bottom + s * 128))[lane];

    // rows 1..26 = gathered embedding rows, 2 rows per iteration
    const int half = lane >> 5;
    const int le = lane & 31;
#pragma unroll
    for (int it = 0; it < 13; ++it) {
        const int r = 1 + it * 2 + half;
        const int tab = r - 1;
        const int idx = cat[s * T_CAT + tab];
        const float4 v =
            *(const float4*)(emb + ((long)tab * V_SZ + idx) * E_SZ + le * 4);
        bf16x4 o;
        o[0] = (bf16)v.x; o[1] = (bf16)v.y; o[2] = (bf16)v.z; o[3] = (bf16)v.w;
        *(bf16x4*)&feats[w][r * 128 + le * 4] = o;
    }
    // rows 27..31 left uninitialized: they only affect Gram rows/cols >= 27,
    // which are never read.
    __syncthreads();

    // Gram = feats @ feats^T via MFMA; A-frag and B-frag have identical layout
    bf16x8 f[2][4];
#pragma unroll
    for (int i = 0; i < 2; ++i)
#pragma unroll
        for (int ks = 0; ks < 4; ++ks)
            f[i][ks] = *(const bf16x8*)&feats[w][(i * 16 + (lane & 15)) * 128 +
                                                 ks * 32 + (lane >> 4) * 8];

    f32x4 a00 = {}, a01 = {}, a11 = {};
#pragma unroll
    for (int ks = 0; ks < 4; ++ks) {
        a00 = __builtin_amdgcn_mfma_f32_16x16x32_bf16(f[0][ks], f[0][ks], a00, 0, 0, 0);
        a01 = __builtin_amdgcn_mfma_f32_16x16x32_bf16(f[0][ks], f[1][ks], a01, 0, 0, 0);
        a11 = __builtin_amdgcn_mfma_f32_16x16x32_bf16(f[1][ks], f[1][ks], a11, 0, 0, 0);
    }

    const int r4 = (lane >> 4) * 4;
    const int cn = lane & 15;
#pragma unroll
    for (int r = 0; r < 4; ++r) {
        gram[w][(r4 + r) * 32 + cn]             = a00[r];
        gram[w][(r4 + r) * 32 + 16 + cn]        = a01[r];
        gram[w][(16 + r4 + r) * 32 + 16 + cn]   = a11[r];
    }
    __syncthreads();

    bf16* trow = top_in + s * 512;
    if (lane < 16)
        ((bf16x8*)trow)[lane] = ((const bf16x8*)(bottom + s * 128))[lane];
    for (int p = lane; p < 351; p += 64) {
        // triu order: base(i) = sum_{u<i}(26-u); j = p - base + i + 1
        int i = 0, b = 0;
        while (b + (26 - i) <= p) { b += 26 - i; ++i; }
        const int j = p - b + i + 1;
        trow[128 + p] = (bf16)gram[w][i * 32 + j];
    }
    if (lane < 33) trow[479 + lane] = (bf16)0.0f;
}

// ---------------------------------------------------------------------------
// Final layer: out[m] = dot(act3[m] (bf16,256), tw4 (fp32)) + tb4. 1 wave/row.
// ---------------------------------------------------------------------------
__global__ __launch_bounds__(256) void gemv_final(const bf16* __restrict__ A,
                                                  const float* __restrict__ w4,
                                                  const float* __restrict__ b4,
                                                  float* __restrict__ out) {
    const int t = threadIdx.x;
    const int lane = t & 63;
    const int w = t >> 6;
    const long m = (long)blockIdx.x * 4 + w;
    const bf16x4 v = *(const bf16x4*)(A + m * 256 + lane * 4);
    const float4 wv = *(const float4*)(w4 + lane * 4);
    float sum = (float)v[0] * wv.x + (float)v[1] * wv.y + (float)v[2] * wv.z +
                (float)v[3] * wv.w;
#pragma unroll
    for (int off = 32; off > 0; off >>= 1) sum += __shfl_down(sum, off);
    if (lane == 0) out[m] = sum + b4[0];
}

// ---------------------------------------------------------------------------
extern "C" void kernel_launch(void* const* d_in, const int* in_sizes, int n_in,
                              void* d_out, int out_size, void* d_ws, size_t ws_size,
                              hipStream_t stream) {
    const float* numerical = (const float*)d_in[0];
    const int*   cat       = (const int*)d_in[1];
    const float* emb       = (const float*)d_in[2];
    const float* bw0 = (const float*)d_in[3];
    const float* bb0 = (const float*)d_in[4];
    const float* bw1 = (const float*)d_in[5];
    const float* bb1 = (const float*)d_in[6];
    const float* bw2 = (const float*)d_in[7];
    const float* bb2 = (const float*)d_in[8];
    const float* tw0 = (const float*)d_in[9];
    const float* tb0 = (const float*)d_in[10];
    const float* tw1 = (const float*)d_in[11];
    const float* tb1 = (const float*)d_in[12];
    const float* tw2 = (const float*)d_in[13];
    const float* tb2 = (const float*)d_in[14];
    const float* tw3 = (const float*)d_in[15];
    const float* tb3 = (const float*)d_in[16];
    const float* tw4 = (const float*)d_in[17];
    const float* tb4 = (const float*)d_in[18];
    float* out = (float*)d_out;

    char* ws = (char*)d_ws;
    size_t off = 0;
    auto alloc = [&](size_t bytes) {
        char* p = ws + off;
        off += (bytes + 255) & ~(size_t)255;
        return p;
    };
    // weights (bf16, transposed N x Kp)
    bf16* wt0b = (bf16*)alloc((size_t)512 * 64 * 2);
    bf16* wt1b = (bf16*)alloc((size_t)256 * 512 * 2);
    bf16* wt2b = (bf16*)alloc((size_t)128 * 256 * 2);
    bf16* wt0t = (bf16*)alloc((size_t)1024 * 512 * 2);
    bf16* wt1t = (bf16*)alloc((size_t)1024 * 1024 * 2);
    bf16* wt2t = (bf16*)alloc((size_t)512 * 1024 * 2);
    bf16* wt3t = (bf16*)alloc((size_t)256 * 512 * 2);
    // activations
    bf16* xpad = (bf16*)alloc((size_t)B_SZ * 64 * 2);
    bf16* h0   = (bf16*)alloc((size_t)B_SZ * 512 * 2);   // also reused as top_in
    bf16* h1   = (bf16*)alloc((size_t)B_SZ * 256 * 2);
    bf16* bot  = (bf16*)alloc((size_t)B_SZ * 128 * 2);
    bf16* t0   = (bf16*)alloc((size_t)B_SZ * 1024 * 2);  // also reused as t2
    bf16* t1   = (bf16*)alloc((size_t)B_SZ * 1024 * 2);  // also reused as t3
    bf16* top_in = h0;
    bf16* t2 = t0;
    bf16* t3 = t1;

    // weight conversions
    convw<<<(64 * 512 + 255) / 256, 256, 0, stream>>>(bw0, wt0b, 16, 512, 64);
    convw<<<(512 * 256 + 255) / 256, 256, 0, stream>>>(bw1, wt1b, 512, 256, 512);
    convw<<<(256 * 128 + 255) / 256, 256, 0, stream>>>(bw2, wt2b, 256, 128, 256);
    convw<<<(512 * 1024 + 255) / 256, 256, 0, stream>>>(tw0, wt0t, 480, 1024, 512);
    convw<<<(1024 * 1024 + 255) / 256, 256, 0, stream>>>(tw1, wt1t, 1024, 1024, 1024);
    convw<<<(1024 * 512 + 255) / 256, 256, 0, stream>>>(tw2, wt2t, 1024, 512, 1024);
    convw<<<(512 * 256 + 255) / 256, 256, 0, stream>>>(tw3, wt3t, 512, 256, 512);

    make_xpad<<<(B_SZ * 64) / 256, 256, 0, stream>>>(numerical, xpad);

    // bottom MLP
    gemm_bt<1><<<dim3(4, 256), 256, 0, stream>>>(xpad, wt0b, bb0, h0, B_SZ, 512, 64);
    gemm_bt<1><<<dim3(2, 256), 256, 0, stream>>>(h0, wt1b, bb1, h1, B_SZ, 256, 512);
    gemm_bt<1><<<dim3(1, 256), 256, 0, stream>>>(h1, wt2b, bb2, bot, B_SZ, 128, 256);

    // gather + interaction + top_in assembly (overwrites h0 region)
    interact_k<<<B_SZ / 4, 256, 0, stream>>>(emb, cat, bot, top_in);

    // top MLP
    gemm_bt<1><<<dim3(8, 256), 256, 0, stream>>>(top_in, wt0t, tb0, t0, B_SZ, 1024, 512);
    gemm_bt<1><<<dim3(8, 256), 256, 0, stream>>>(t0, wt1t, tb1, t1, B_SZ, 1024, 1024);
    gemm_bt<1><<<dim3(4, 256), 256, 0, stream>>>(t1, wt2t, tb2, t2, B_SZ, 512, 1024);
    gemm_bt<1><<<dim3(2, 256), 256, 0, stream>>>(t2, wt3t, tb3, t3, B_SZ, 256, 512);

    gemv_final<<<B_SZ / 4, 256, 0, stream>>>(t3, tw4, tb4, out);
}

// Round 2
// 425.365 us; speedup vs baseline: 1.0531x; 1.0531x over previous
//
#include <hip/hip_runtime.h>

typedef __bf16 bf16;
typedef __bf16 bf16x4 __attribute__((ext_vector_type(4)));
typedef __bf16 bf16x8 __attribute__((ext_vector_type(8)));
typedef float f32x4 __attribute__((ext_vector_type(4)));

#define B_SZ 32768
#define T_CAT 26
#define V_SZ 100000
#define E_SZ 128

__device__ __forceinline__ void gload_lds16(const void* g, void* l) {
    __builtin_amdgcn_global_load_lds(
        (const __attribute__((address_space(1))) void*)g,
        (__attribute__((address_space(3))) void*)l, 16, 0, 0);
}

// ---------------------------------------------------------------------------
// Weight convert: W (K x N fp32, row-major) -> Wt (N x Kp bf16, row-major),
// zero-padded for k in [K, Kp). Reads coalesced along n.
// ---------------------------------------------------------------------------
__global__ __launch_bounds__(256) void convw(const float* __restrict__ W,
                                             bf16* __restrict__ Wt,
                                             int K, int N, int Kp) {
    const int idx = blockIdx.x * 256 + threadIdx.x;
    if (idx >= Kp * N) return;
    const int k = idx / N;
    const int n = idx - k * N;
    const float v = (k < K) ? W[(long)k * N + n] : 0.0f;
    Wt[(long)n * Kp + k] = (bf16)v;
}

// numerical (B x 13 fp32) -> xpad (B x 64 bf16), cols 13..63 zero
__global__ __launch_bounds__(256) void make_xpad(const float* __restrict__ num,
                                                 bf16* __restrict__ xp) {
    const int idx = blockIdx.x * 256 + threadIdx.x;  // B*64 threads
    const int b = idx >> 6, c = idx & 63;
    xp[idx] = (bf16)((c < 13) ? num[(long)b * 13 + c] : 0.0f);
}

// ---------------------------------------------------------------------------
// 128x128 tile GEMM (m97 structure) — used for bottom MLP + last top layer.
// ---------------------------------------------------------------------------
template <int RELU>
__global__ __launch_bounds__(256) void gemm_bt(const bf16* __restrict__ A,
                                               const bf16* __restrict__ Bt,
                                               const float* __restrict__ bias,
                                               bf16* __restrict__ C,
                                               int M, int N, int K) {
    __shared__ __align__(16) bf16 As[128 * 64];
    __shared__ __align__(16) bf16 Bs[128 * 64];
    const int t = threadIdx.x;
    const int lane = t & 63;
    const int w = t >> 6;
    const int wm = w >> 1, wn = w & 1;
    const long row0 = (long)blockIdx.y * 128;
    const long col0 = (long)blockIdx.x * 128;

    const int srow = t >> 3;
    const int scol = (t & 7) * 8;
    const bf16* Ag = A + (row0 + srow) * (long)K + scol;
    const bf16* Bg = Bt + (col0 + srow) * (long)K + scol;
    bf16* AsB = &As[w * 512];
    bf16* BsB = &Bs[w * 512];

    f32x4 acc[4][4] = {};

    for (int k0 = 0; k0 < K; k0 += 64) {
#pragma unroll
        for (int q = 0; q < 4; ++q) {
            gload_lds16(Ag + (long)q * 32 * K + k0, AsB + q * 2048);
            gload_lds16(Bg + (long)q * 32 * K + k0, BsB + q * 2048);
        }
        __syncthreads();
#pragma unroll
        for (int s = 0; s < 2; ++s) {
            bf16x8 af[4], bv[4];
#pragma unroll
            for (int i = 0; i < 4; ++i)
                af[i] = *(const bf16x8*)&As[(wm * 64 + i * 16 + (lane & 15)) * 64 +
                                            s * 32 + (lane >> 4) * 8];
#pragma unroll
            for (int j = 0; j < 4; ++j)
                bv[j] = *(const bf16x8*)&Bs[(wn * 64 + j * 16 + (lane & 15)) * 64 +
                                            s * 32 + (lane >> 4) * 8];
#pragma unroll
            for (int i = 0; i < 4; ++i)
#pragma unroll
                for (int j = 0; j < 4; ++j)
                    acc[i][j] = __builtin_amdgcn_mfma_f32_16x16x32_bf16(
                        af[i], bv[j], acc[i][j], 0, 0, 0);
        }
        __syncthreads();
    }

    const int r4 = (lane >> 4) * 4;
    const int cn = lane & 15;
#pragma unroll
    for (int j = 0; j < 4; ++j) {
        const long col = col0 + wn * 64 + j * 16 + cn;
        const float bj = bias[col];
#pragma unroll
        for (int i = 0; i < 4; ++i) {
#pragma unroll
            for (int r = 0; r < 4; ++r) {
                const long row = row0 + wm * 64 + i * 16 + r4 + r;
                float v = acc[i][j][r] + bj;
                if (RELU) v = v > 0.0f ? v : 0.0f;
                C[row * (long)N + col] = (bf16)v;
            }
        }
    }
}

// ---------------------------------------------------------------------------
// 256x256 tile GEMM, BK=32, 4-deep LDS ring, counted vmcnt (never 0 in
// steady state), raw s_barrier, setprio around MFMA, 2-way-swizzled LDS.
// 8 waves (2x4), wave tile 128x64. Requires M%256==0, N%256==0, K%32==0,
// K/32 >= 4, grid%8 == 0 (XCD swizzle).
// LDS swizzle: LDS[row][slot16B] holds G[row][slot ^ ((row>>1)&3)] — applied
// on the per-lane GLOBAL source (gload_lds dest is linear) and on the read.
// ---------------------------------------------------------------------------
template <int RELU>
__global__ __launch_bounds__(512, 2) void gemm256(const bf16* __restrict__ A,
                                                  const bf16* __restrict__ Bt,
                                                  const float* __restrict__ bias,
                                                  bf16* __restrict__ C,
                                                  int M, int N, int K, int nbx) {
    // [buf(4)][A/B(2)][256 rows][32 k] bf16 = 128 KiB
    __shared__ __align__(16) bf16 lds[4 * 2 * 8192];
    const int t = threadIdx.x;
    const int lane = t & 63;
    const int w = t >> 6;            // 0..7
    const int wm = w >> 2, wn = w & 3;

    // bijective XCD swizzle (gridDim.x % 8 == 0): consecutive swz ids share
    // an XCD, so blocks sharing an A-panel co-reside in one L2.
    const int nwg = gridDim.x;
    const int qch = nwg >> 3;
    const int swz = ((int)blockIdx.x & 7) * qch + ((int)blockIdx.x >> 3);
    const int bx = swz % nbx, by = swz / nbx;
    const long row0 = (long)by * 256;
    const long col0 = (long)bx * 256;

    const int NT = K >> 5;

    // staging: per tile 4 gload_lds/thread (A q=0,1; B q=0,1).
    // instr (w,q) covers LDS rows (w*2+q)*16 .. +15; lane -> row lr0+(lane>>2),
    // 16B slot (lane&3). Source pre-swizzled: slot d holds G[row][d ^ s(row)].
    const int lr = lane >> 2;
    const int dslot = lane & 3;
    const int lrow0 = (w * 2 + 0) * 16 + lr;
    const int lrow1 = (w * 2 + 1) * 16 + lr;
    const int sl0 = dslot ^ ((lrow0 >> 1) & 3);
    const int sl1 = dslot ^ ((lrow1 >> 1) & 3);
    const bf16* Ag0 = A + (row0 + lrow0) * (long)K + sl0 * 8;
    const bf16* Ag1 = A + (row0 + lrow1) * (long)K + sl1 * 8;
    const bf16* Bg0 = Bt + (col0 + lrow0) * (long)K + sl0 * 8;
    const bf16* Bg1 = Bt + (col0 + lrow1) * (long)K + sl1 * 8;
    const int ldsRow0 = (w * 2 + 0) * 512;  // elements
    const int ldsRow1 = (w * 2 + 1) * 512;

#define STAGE256(buf, kt)                                                  \
    do {                                                                   \
        const int _k0 = (kt) << 5;                                         \
        gload_lds16(Ag0 + _k0, &lds[((buf) * 2 + 0) * 8192 + ldsRow0]);    \
        gload_lds16(Ag1 + _k0, &lds[((buf) * 2 + 0) * 8192 + ldsRow1]);    \
        gload_lds16(Bg0 + _k0, &lds[((buf) * 2 + 1) * 8192 + ldsRow0]);    \
        gload_lds16(Bg1 + _k0, &lds[((buf) * 2 + 1) * 8192 + ldsRow1]);    \
    } while (0)

    // fragment read offsets (elements, within one 8192-elem tile), constant
    // across iterations. lane: row (lane&15)+16i, k-chunk (lane>>4) swizzled.
    const int cm = lane & 15;
    const int kc = lane >> 4;
    int aoff[8], boff[4];
#pragma unroll
    for (int i = 0; i < 8; ++i) {
        const int r = wm * 128 + i * 16 + cm;
        aoff[i] = r * 32 + (kc ^ ((r >> 1) & 3)) * 8;
    }
#pragma unroll
    for (int j = 0; j < 4; ++j) {
        const int n = wn * 64 + j * 16 + cm;
        boff[j] = n * 32 + (kc ^ ((n >> 1) & 3)) * 8;
    }

    f32x4 acc[8][4] = {};

    STAGE256(0, 0);
    STAGE256(1, 1);
    STAGE256(2, 2);

    for (int tt = 0; tt < NT; ++tt) {
        const int rem = NT - 1 - tt;
        if (rem >= 3) {
            STAGE256((tt + 3) & 3, tt + 3);
            asm volatile("s_waitcnt vmcnt(12)" ::: "memory");  // tile tt landed
        } else if (rem == 2) {
            asm volatile("s_waitcnt vmcnt(8)" ::: "memory");
        } else if (rem == 1) {
            asm volatile("s_waitcnt vmcnt(4)" ::: "memory");
        } else {
            asm volatile("s_waitcnt vmcnt(0)" ::: "memory");
        }
        __builtin_amdgcn_s_barrier();  // all waves' tile-tt staging visible
        asm volatile("" ::: "memory");

        const bf16* Ab = &lds[((tt & 3) * 2 + 0) * 8192];
        const bf16* Bb = &lds[((tt & 3) * 2 + 1) * 8192];
        bf16x8 af[8], bfr[4];
#pragma unroll
        for (int j = 0; j < 4; ++j) bfr[j] = *(const bf16x8*)&Bb[boff[j]];
#pragma unroll
        for (int i = 0; i < 8; ++i) af[i] = *(const bf16x8*)&Ab[aoff[i]];

        __builtin_amdgcn_s_setprio(1);
#pragma unroll
        for (int i = 0; i < 8; ++i)
#pragma unroll
            for (int j = 0; j < 4; ++j)
                acc[i][j] = __builtin_amdgcn_mfma_f32_16x16x32_bf16(
                    af[i], bfr[j], acc[i][j], 0, 0, 0);
        __builtin_amdgcn_s_setprio(0);
        asm volatile("" ::: "memory");
        __builtin_amdgcn_s_barrier();  // reads of buf[tt&3] done before reuse
    }
#undef STAGE256

    // epilogue: D row = (lane>>4)*4 + reg, col = lane&15
    const int r4 = kc * 4;
#pragma unroll
    for (int j = 0; j < 4; ++j) {
        const long col = col0 + wn * 64 + j * 16 + cm;
        const float bj = bias[col];
#pragma unroll
        for (int i = 0; i < 8; ++i) {
#pragma unroll
            for (int r = 0; r < 4; ++r) {
                const long row = row0 + wm * 128 + i * 16 + r4 + r;
                float v = acc[i][j][r] + bj;
                if (RELU) v = v > 0.0f ? v : 0.0f;
                C[row * (long)N + col] = (bf16)v;
            }
        }
    }
}

// ---------------------------------------------------------------------------
// Fused embedding gather + pairwise interaction + top_in assembly.
// ---------------------------------------------------------------------------
__global__ __launch_bounds__(256) void interact_k(const float* __restrict__ emb,
                                                  const int* __restrict__ cat,
                                                  const bf16* __restrict__ bottom,
                                                  bf16* __restrict__ top_in) {
    __shared__ __align__(16) bf16 feats[4][32 * 128];
    __shared__ float gram[4][32 * 32];
    const int t = threadIdx.x;
    const int lane = t & 63;
    const int w = t >> 6;
    const long s = (long)blockIdx.x * 4 + w;

    if (lane < 16)
        ((bf16x8*)&feats[w][0])[lane] = ((const bf16x8*)(bottom + s * 128))[lane];

    const int half = lane >> 5;
    const int le = lane & 31;
#pragma unroll
    for (int it = 0; it < 13; ++it) {
        const int r = 1 + it * 2 + half;
        const int tab = r - 1;
        const int idx = cat[s * T_CAT + tab];
        const float4 v =
            *(const float4*)(emb + ((long)tab * V_SZ + idx) * E_SZ + le * 4);
        bf16x4 o;
        o[0] = (bf16)v.x; o[1] = (bf16)v.y; o[2] = (bf16)v.z; o[3] = (bf16)v.w;
        *(bf16x4*)&feats[w][r * 128 + le * 4] = o;
    }
    __syncthreads();

    bf16x8 f[2][4];
#pragma unroll
    for (int i = 0; i < 2; ++i)
#pragma unroll
        for (int ks = 0; ks < 4; ++ks)
            f[i][ks] = *(const bf16x8*)&feats[w][(i * 16 + (lane & 15)) * 128 +
                                                 ks * 32 + (lane >> 4) * 8];

    f32x4 a00 = {}, a01 = {}, a11 = {};
#pragma unroll
    for (int ks = 0; ks < 4; ++ks) {
        a00 = __builtin_amdgcn_mfma_f32_16x16x32_bf16(f[0][ks], f[0][ks], a00, 0, 0, 0);
        a01 = __builtin_amdgcn_mfma_f32_16x16x32_bf16(f[0][ks], f[1][ks], a01, 0, 0, 0);
        a11 = __builtin_amdgcn_mfma_f32_16x16x32_bf16(f[1][ks], f[1][ks], a11, 0, 0, 0);
    }

    const int r4 = (lane >> 4) * 4;
    const int cn = lane & 15;
#pragma unroll
    for (int r = 0; r < 4; ++r) {
        gram[w][(r4 + r) * 32 + cn]           = a00[r];
        gram[w][(r4 + r) * 32 + 16 + cn]      = a01[r];
        gram[w][(16 + r4 + r) * 32 + 16 + cn] = a11[r];
    }
    __syncthreads();

    bf16* trow = top_in + s * 512;
    if (lane < 16)
        ((bf16x8*)trow)[lane] = ((const bf16x8*)(bottom + s * 128))[lane];
    for (int p = lane; p < 351; p += 64) {
        int i = 0, b = 0;
        while (b + (26 - i) <= p) { b += 26 - i; ++i; }
        const int j = p - b + i + 1;
        trow[128 + p] = (bf16)gram[w][i * 32 + j];
    }
    if (lane < 33) trow[479 + lane] = (bf16)0.0f;
}

// ---------------------------------------------------------------------------
// Final layer: out[m] = dot(act3[m] (bf16,256), tw4 (fp32)) + tb4.
// ---------------------------------------------------------------------------
__global__ __launch_bounds__(256) void gemv_final(const bf16* __restrict__ A,
                                                  const float* __restrict__ w4,
                                                  const float* __restrict__ b4,
                                                  float* __restrict__ out) {
    const int t = threadIdx.x;
    const int lane = t & 63;
    const int w = t >> 6;
    const long m = (long)blockIdx.x * 4 + w;
    const bf16x4 v = *(const bf16x4*)(A + m * 256 + lane * 4);
    const float4 wv = *(const float4*)(w4 + lane * 4);
    float sum = (float)v[0] * wv.x + (float)v[1] * wv.y + (float)v[2] * wv.z +
                (float)v[3] * wv.w;
#pragma unroll
    for (int off = 32; off > 0; off >>= 1) sum += __shfl_down(sum, off);
    if (lane == 0) out[m] = sum + b4[0];
}

// ---------------------------------------------------------------------------
extern "C" void kernel_launch(void* const* d_in, const int* in_sizes, int n_in,
                              void* d_out, int out_size, void* d_ws, size_t ws_size,
                              hipStream_t stream) {
    const float* numerical = (const float*)d_in[0];
    const int*   cat       = (const int*)d_in[1];
    const float* emb       = (const float*)d_in[2];
    const float* bw0 = (const float*)d_in[3];
    const float* bb0 = (const float*)d_in[4];
    const float* bw1 = (const float*)d_in[5];
    const float* bb1 = (const float*)d_in[6];
    const float* bw2 = (const float*)d_in[7];
    const float* bb2 = (const float*)d_in[8];
    const float* tw0 = (const float*)d_in[9];
    const float* tb0 = (const float*)d_in[10];
    const float* tw1 = (const float*)d_in[11];
    const float* tb1 = (const float*)d_in[12];
    const float* tw2 = (const float*)d_in[13];
    const float* tb2 = (const float*)d_in[14];
    const float* tw3 = (const float*)d_in[15];
    const float* tb3 = (const float*)d_in[16];
    const float* tw4 = (const float*)d_in[17];
    const float* tb4 = (const float*)d_in[18];
    float* out = (float*)d_out;

    char* ws = (char*)d_ws;
    size_t off = 0;
    auto alloc = [&](size_t bytes) {
        char* p = ws + off;
        off += (bytes + 255) & ~(size_t)255;
        return p;
    };
    bf16* wt0b = (bf16*)alloc((size_t)512 * 64 * 2);
    bf16* wt1b = (bf16*)alloc((size_t)256 * 512 * 2);
    bf16* wt2b = (bf16*)alloc((size_t)128 * 256 * 2);
    bf16* wt0t = (bf16*)alloc((size_t)1024 * 512 * 2);
    bf16* wt1t = (bf16*)alloc((size_t)1024 * 1024 * 2);
    bf16* wt2t = (bf16*)alloc((size_t)512 * 1024 * 2);
    bf16* wt3t = (bf16*)alloc((size_t)256 * 512 * 2);
    bf16* xpad = (bf16*)alloc((size_t)B_SZ * 64 * 2);
    bf16* h0   = (bf16*)alloc((size_t)B_SZ * 512 * 2);
    bf16* h1   = (bf16*)alloc((size_t)B_SZ * 256 * 2);
    bf16* bot  = (bf16*)alloc((size_t)B_SZ * 128 * 2);
    bf16* t0   = (bf16*)alloc((size_t)B_SZ * 1024 * 2);
    bf16* t1   = (bf16*)alloc((size_t)B_SZ * 1024 * 2);
    bf16* top_in = h0;
    bf16* t2 = t0;
    bf16* t3 = t1;

    convw<<<(64 * 512 + 255) / 256, 256, 0, stream>>>(bw0, wt0b, 16, 512, 64);
    convw<<<(512 * 256 + 255) / 256, 256, 0, stream>>>(bw1, wt1b, 512, 256, 512);
    convw<<<(256 * 128 + 255) / 256, 256, 0, stream>>>(bw2, wt2b, 256, 128, 256);
    convw<<<(512 * 1024 + 255) / 256, 256, 0, stream>>>(tw0, wt0t, 480, 1024, 512);
    convw<<<(1024 * 1024 + 255) / 256, 256, 0, stream>>>(tw1, wt1t, 1024, 1024, 1024);
    convw<<<(1024 * 512 + 255) / 256, 256, 0, stream>>>(tw2, wt2t, 1024, 512, 1024);
    convw<<<(512 * 256 + 255) / 256, 256, 0, stream>>>(tw3, wt3t, 512, 256, 512);

    make_xpad<<<(B_SZ * 64) / 256, 256, 0, stream>>>(numerical, xpad);

    // bottom MLP (128^2 kernel)
    gemm_bt<1><<<dim3(4, 256), 256, 0, stream>>>(xpad, wt0b, bb0, h0, B_SZ, 512, 64);
    gemm_bt<1><<<dim3(2, 256), 256, 0, stream>>>(h0, wt1b, bb1, h1, B_SZ, 256, 512);
    gemm_bt<1><<<dim3(1, 256), 256, 0, stream>>>(h1, wt2b, bb2, bot, B_SZ, 128, 256);

    interact_k<<<B_SZ / 4, 256, 0, stream>>>(emb, cat, bot, top_in);

    // top MLP: big 3 layers on the deep-pipelined 256^2 kernel
    gemm256<1><<<dim3(4 * 128), 512, 0, stream>>>(top_in, wt0t, tb0, t0, B_SZ, 1024, 512, 4);
    gemm256<1><<<dim3(4 * 128), 512, 0, stream>>>(t0, wt1t, tb1, t1, B_SZ, 1024, 1024, 4);
    gemm256<1><<<dim3(2 * 128), 512, 0, stream>>>(t1, wt2t, tb2, t2, B_SZ, 512, 1024, 2);
    gemm_bt<1><<<dim3(2, 256), 256, 0, stream>>>(t2, wt3t, tb3, t3, B_SZ, 256, 512);

    gemv_final<<<B_SZ / 4, 256, 0, stream>>>(t3, tw4, tb4, out);
}

// Round 3
// 394.590 us; speedup vs baseline: 1.1352x; 1.0780x over previous
//
#include <hip/hip_runtime.h>

typedef __bf16 bf16;
typedef __bf16 bf16x4 __attribute__((ext_vector_type(4)));
typedef __bf16 bf16x8 __attribute__((ext_vector_type(8)));
typedef float f32x4 __attribute__((ext_vector_type(4)));

#define B_SZ 32768
#define T_CAT 26
#define V_SZ 100000
#define E_SZ 128

__device__ __forceinline__ void gload_lds16(const void* g, void* l) {
    __builtin_amdgcn_global_load_lds(
        (const __attribute__((address_space(1))) void*)g,
        (__attribute__((address_space(3))) void*)l, 16, 0, 0);
}

// ---------------------------------------------------------------------------
// Merged weight convert: all 7 weights, W (K x N fp32) -> Wt (N x Kp bf16).
// ---------------------------------------------------------------------------
struct CJob { const float* W; bf16* Wt; int K, N, Kp, blk0; };
struct CJobs { CJob j[7]; };

__global__ __launch_bounds__(256) void convw_all(CJobs js) {
    const int b = blockIdx.x;
    int ji = 0;
#pragma unroll
    for (int k = 1; k < 7; ++k)
        if (b >= js.j[k].blk0) ji = k;
    const CJob J = js.j[ji];
    const int idx = (b - J.blk0) * 256 + threadIdx.x;
    if (idx >= J.Kp * J.N) return;
    const int k = idx / J.N;
    const int n = idx - k * J.N;
    const float v = (k < J.K) ? J.W[(long)k * J.N + n] : 0.0f;
    J.Wt[(long)n * J.Kp + k] = (bf16)v;
}

// numerical (B x 13 fp32) -> xpad (B x 64 bf16), cols 13..63 zero
__global__ __launch_bounds__(256) void make_xpad(const float* __restrict__ num,
                                                 bf16* __restrict__ xp) {
    const int idx = blockIdx.x * 256 + threadIdx.x;  // B*64 threads
    const int b = idx >> 6, c = idx & 63;
    xp[idx] = (bf16)((c < 13) ? num[(long)b * 13 + c] : 0.0f);
}

// ---------------------------------------------------------------------------
// 128x128 tile GEMM (m97 structure) — bottom MLP + last top layer.
// ---------------------------------------------------------------------------
template <int RELU>
__global__ __launch_bounds__(256) void gemm_bt(const bf16* __restrict__ A,
                                               const bf16* __restrict__ Bt,
                                               const float* __restrict__ bias,
                                               bf16* __restrict__ C,
                                               int M, int N, int K) {
    __shared__ __align__(16) bf16 As[128 * 64];
    __shared__ __align__(16) bf16 Bs[128 * 64];
    const int t = threadIdx.x;
    const int lane = t & 63;
    const int w = t >> 6;
    const int wm = w >> 1, wn = w & 1;
    const long row0 = (long)blockIdx.y * 128;
    const long col0 = (long)blockIdx.x * 128;

    const int srow = t >> 3;
    const int scol = (t & 7) * 8;
    const bf16* Ag = A + (row0 + srow) * (long)K + scol;
    const bf16* Bg = Bt + (col0 + srow) * (long)K + scol;
    bf16* AsB = &As[w * 512];
    bf16* BsB = &Bs[w * 512];

    f32x4 acc[4][4] = {};

    for (int k0 = 0; k0 < K; k0 += 64) {
#pragma unroll
        for (int q = 0; q < 4; ++q) {
            gload_lds16(Ag + (long)q * 32 * K + k0, AsB + q * 2048);
            gload_lds16(Bg + (long)q * 32 * K + k0, BsB + q * 2048);
        }
        __syncthreads();
#pragma unroll
        for (int s = 0; s < 2; ++s) {
            bf16x8 af[4], bv[4];
#pragma unroll
            for (int i = 0; i < 4; ++i)
                af[i] = *(const bf16x8*)&As[(wm * 64 + i * 16 + (lane & 15)) * 64 +
                                            s * 32 + (lane >> 4) * 8];
#pragma unroll
            for (int j = 0; j < 4; ++j)
                bv[j] = *(const bf16x8*)&Bs[(wn * 64 + j * 16 + (lane & 15)) * 64 +
                                            s * 32 + (lane >> 4) * 8];
#pragma unroll
            for (int i = 0; i < 4; ++i)
#pragma unroll
                for (int j = 0; j < 4; ++j)
                    acc[i][j] = __builtin_amdgcn_mfma_f32_16x16x32_bf16(
                        af[i], bv[j], acc[i][j], 0, 0, 0);
        }
        __syncthreads();
    }

    const int r4 = (lane >> 4) * 4;
    const int cn = lane & 15;
#pragma unroll
    for (int j = 0; j < 4; ++j) {
        const long col = col0 + wn * 64 + j * 16 + cn;
        const float bj = bias[col];
#pragma unroll
        for (int i = 0; i < 4; ++i) {
#pragma unroll
            for (int r = 0; r < 4; ++r) {
                const long row = row0 + wm * 64 + i * 16 + r4 + r;
                float v = acc[i][j][r] + bj;
                if (RELU) v = v > 0.0f ? v : 0.0f;
                C[row * (long)N + col] = (bf16)v;
            }
        }
    }
}

// ---------------------------------------------------------------------------
// 256x256 tile GEMM, BK=32, 4-deep LDS ring, counted vmcnt, 2-phase per-tile
// interleave (ds_read ∥ stage ∥ MFMA), setprio around MFMA clusters,
// 2-way-swizzled LDS. 8 waves (2x4), wave tile 128x64.
// Requires M%256==0, N%256==0, K%32==0, K/32 >= 4, grid%8 == 0.
// ---------------------------------------------------------------------------
template <int RELU>
__global__ __launch_bounds__(512, 2) void gemm256(const bf16* __restrict__ A,
                                                  const bf16* __restrict__ Bt,
                                                  const float* __restrict__ bias,
                                                  bf16* __restrict__ C,
                                                  int M, int N, int K, int nbx) {
    // [buf(4)][A/B(2)][256 rows][32 k] bf16 = 128 KiB
    __shared__ __align__(16) bf16 lds[4 * 2 * 8192];
    const int t = threadIdx.x;
    const int lane = t & 63;
    const int w = t >> 6;            // 0..7
    const int wm = w >> 2, wn = w & 3;

    // bijective XCD swizzle (gridDim.x % 8 == 0)
    const int nwg = gridDim.x;
    const int qch = nwg >> 3;
    const int swz = ((int)blockIdx.x & 7) * qch + ((int)blockIdx.x >> 3);
    const int bx = swz % nbx, by = swz / nbx;
    const long row0 = (long)by * 256;
    const long col0 = (long)bx * 256;

    const int NT = K >> 5;

    // staging: per tile 4 gload_lds/thread (A r0, A r1, B r0, B r1).
    // instr (w,q) covers LDS rows (w*2+q)*16..+15; lane -> row +(lane>>2),
    // 16B slot (lane&3). Source pre-swizzled: LDS slot d holds G[row][d^s(row)].
    const int lr = lane >> 2;
    const int dslot = lane & 3;
    const int lrow0 = (w * 2 + 0) * 16 + lr;
    const int lrow1 = (w * 2 + 1) * 16 + lr;
    const int sl0 = dslot ^ ((lrow0 >> 1) & 3);
    const int sl1 = dslot ^ ((lrow1 >> 1) & 3);
    const bf16* Ag0 = A + (row0 + lrow0) * (long)K + sl0 * 8;
    const bf16* Ag1 = A + (row0 + lrow1) * (long)K + sl1 * 8;
    const bf16* Bg0 = Bt + (col0 + lrow0) * (long)K + sl0 * 8;
    const bf16* Bg1 = Bt + (col0 + lrow1) * (long)K + sl1 * 8;
    const int ldsRow0 = (w * 2 + 0) * 512;  // elements
    const int ldsRow1 = (w * 2 + 1) * 512;

#define STAGE_A(buf, kt)                                                   \
    do {                                                                   \
        const int _k0 = (kt) << 5;                                         \
        gload_lds16(Ag0 + _k0, &lds[((buf) * 2 + 0) * 8192 + ldsRow0]);    \
        gload_lds16(Ag1 + _k0, &lds[((buf) * 2 + 0) * 8192 + ldsRow1]);    \
    } while (0)
#define STAGE_B(buf, kt)                                                   \
    do {                                                                   \
        const int _k0 = (kt) << 5;                                         \
        gload_lds16(Bg0 + _k0, &lds[((buf) * 2 + 1) * 8192 + ldsRow0]);    \
        gload_lds16(Bg1 + _k0, &lds[((buf) * 2 + 1) * 8192 + ldsRow1]);    \
    } while (0)

    // fragment read offsets (elements within one 8192-elem tile)
    const int cm = lane & 15;
    const int kc = lane >> 4;
    int aoff[8], boff[4];
#pragma unroll
    for (int i = 0; i < 8; ++i) {
        const int r = wm * 128 + i * 16 + cm;
        aoff[i] = r * 32 + (kc ^ ((r >> 1) & 3)) * 8;
    }
#pragma unroll
    for (int j = 0; j < 4; ++j) {
        const int n = wn * 64 + j * 16 + cm;
        boff[j] = n * 32 + (kc ^ ((n >> 1) & 3)) * 8;
    }

    f32x4 acc[8][4] = {};

    STAGE_A(0, 0); STAGE_B(0, 0);
    STAGE_A(1, 1); STAGE_B(1, 1);
    STAGE_A(2, 2); STAGE_B(2, 2);

    for (int tt = 0; tt < NT; ++tt) {
        const int rem = NT - 1 - tt;
        const int sb = (tt + 3) & 3;
        const int sk = tt + 3;

        // tile tt ready across all waves
        if (rem >= 2)      asm volatile("s_waitcnt vmcnt(8)" ::: "memory");
        else if (rem == 1) asm volatile("s_waitcnt vmcnt(4)" ::: "memory");
        else               asm volatile("s_waitcnt vmcnt(0)" ::: "memory");
        __builtin_amdgcn_s_barrier();

        const bf16* Ab = &lds[((tt & 3) * 2 + 0) * 8192];
        const bf16* Bb = &lds[((tt & 3) * 2 + 1) * 8192];

        // ---- Phase 1: read B-frags + A-frags 0-3, stage A-half of tt+3 ----
        bf16x8 bfr[4], af[4];
#pragma unroll
        for (int j = 0; j < 4; ++j) bfr[j] = *(const bf16x8*)&Bb[boff[j]];
#pragma unroll
        for (int i = 0; i < 4; ++i) af[i] = *(const bf16x8*)&Ab[aoff[i]];
        if (rem >= 3) STAGE_A(sb, sk);
        __builtin_amdgcn_s_barrier();
        __builtin_amdgcn_s_setprio(1);
#pragma unroll
        for (int i = 0; i < 4; ++i)
#pragma unroll
            for (int j = 0; j < 4; ++j)
                acc[i][j] = __builtin_amdgcn_mfma_f32_16x16x32_bf16(
                    af[i], bfr[j], acc[i][j], 0, 0, 0);
        __builtin_amdgcn_s_setprio(0);

        // ---- Phase 2: read A-frags 4-7, stage B-half of tt+3 ----
        bf16x8 af2[4];
#pragma unroll
        for (int i = 0; i < 4; ++i) af2[i] = *(const bf16x8*)&Ab[aoff[4 + i]];
        if (rem >= 3) STAGE_B(sb, sk);
        __builtin_amdgcn_s_barrier();
        __builtin_amdgcn_s_setprio(1);
#pragma unroll
        for (int i = 0; i < 4; ++i)
#pragma unroll
            for (int j = 0; j < 4; ++j)
                acc[4 + i][j] = __builtin_amdgcn_mfma_f32_16x16x32_bf16(
                    af2[i], bfr[j], acc[4 + i][j], 0, 0, 0);
        __builtin_amdgcn_s_setprio(0);
    }
#undef STAGE_A
#undef STAGE_B

    // epilogue: D row = (lane>>4)*4 + reg, col = lane&15
    const int r4 = kc * 4;
#pragma unroll
    for (int j = 0; j < 4; ++j) {
        const long col = col0 + wn * 64 + j * 16 + cm;
        const float bj = bias[col];
#pragma unroll
        for (int i = 0; i < 8; ++i) {
#pragma unroll
            for (int r = 0; r < 4; ++r) {
                const long row = row0 + wm * 128 + i * 16 + r4 + r;
                float v = acc[i][j][r] + bj;
                if (RELU) v = v > 0.0f ? v : 0.0f;
                C[row * (long)N + col] = (bf16)v;
            }
        }
    }
}

// ---------------------------------------------------------------------------
// Fused embedding gather + pairwise interaction + top_in assembly.
// Output row assembled in LDS, stored as one coalesced 16B/lane wave store.
// ---------------------------------------------------------------------------
__global__ __launch_bounds__(256) void interact_k(const float* __restrict__ emb,
                                                  const int* __restrict__ cat,
                                                  const bf16* __restrict__ bottom,
                                                  bf16* __restrict__ top_in) {
    __shared__ __align__(16) bf16 feats[4][32 * 128];
    __shared__ float gram[4][32 * 32];
    __shared__ __align__(16) bf16 rowbuf[4][512];
    const int t = threadIdx.x;
    const int lane = t & 63;
    const int w = t >> 6;
    const long s = (long)blockIdx.x * 4 + w;

    if (lane < 16)
        ((bf16x8*)&feats[w][0])[lane] = ((const bf16x8*)(bottom + s * 128))[lane];

    const int half = lane >> 5;
    const int le = lane & 31;
#pragma unroll
    for (int it = 0; it < 13; ++it) {
        const int r = 1 + it * 2 + half;
        const int tab = r - 1;
        const int idx = cat[s * T_CAT + tab];
        const float4 v =
            *(const float4*)(emb + ((long)tab * V_SZ + idx) * E_SZ + le * 4);
        bf16x4 o;
        o[0] = (bf16)v.x; o[1] = (bf16)v.y; o[2] = (bf16)v.z; o[3] = (bf16)v.w;
        *(bf16x4*)&feats[w][r * 128 + le * 4] = o;
    }
    __syncthreads();

    bf16x8 f[2][4];
#pragma unroll
    for (int i = 0; i < 2; ++i)
#pragma unroll
        for (int ks = 0; ks < 4; ++ks)
            f[i][ks] = *(const bf16x8*)&feats[w][(i * 16 + (lane & 15)) * 128 +
                                                 ks * 32 + (lane >> 4) * 8];

    f32x4 a00 = {}, a01 = {}, a11 = {};
#pragma unroll
    for (int ks = 0; ks < 4; ++ks) {
        a00 = __builtin_amdgcn_mfma_f32_16x16x32_bf16(f[0][ks], f[0][ks], a00, 0, 0, 0);
        a01 = __builtin_amdgcn_mfma_f32_16x16x32_bf16(f[0][ks], f[1][ks], a01, 0, 0, 0);
        a11 = __builtin_amdgcn_mfma_f32_16x16x32_bf16(f[1][ks], f[1][ks], a11, 0, 0, 0);
    }

    const int r4 = (lane >> 4) * 4;
    const int cn = lane & 15;
#pragma unroll
    for (int r = 0; r < 4; ++r) {
        gram[w][(r4 + r) * 32 + cn]           = a00[r];
        gram[w][(r4 + r) * 32 + 16 + cn]      = a01[r];
        gram[w][(16 + r4 + r) * 32 + 16 + cn] = a11[r];
    }
    __syncthreads();

    // assemble the 512-wide top_in row in LDS
    if (lane < 16)
        ((bf16x8*)&rowbuf[w][0])[lane] = ((const bf16x8*)&feats[w][0])[lane];
    for (int p = lane; p < 351; p += 64) {
        int i = 0, b = 0;
        while (b + (26 - i) <= p) { b += 26 - i; ++i; }
        const int j = p - b + i + 1;
        rowbuf[w][128 + p] = (bf16)gram[w][i * 32 + j];
    }
    if (lane >= 31) rowbuf[w][448 + lane] = (bf16)0.0f;  // 479..511
    __syncthreads();

    *(bf16x8*)(top_in + s * 512 + lane * 8) = *(const bf16x8*)&rowbuf[w][lane * 8];
}

// ---------------------------------------------------------------------------
// Final layer: out[m] = dot(act3[m] (bf16,256), tw4 (fp32)) + tb4.
// ---------------------------------------------------------------------------
__global__ __launch_bounds__(256) void gemv_final(const bf16* __restrict__ A,
                                                  const float* __restrict__ w4,
                                                  const float* __restrict__ b4,
                                                  float* __restrict__ out) {
    const int t = threadIdx.x;
    const int lane = t & 63;
    const int w = t >> 6;
    const long m = (long)blockIdx.x * 4 + w;
    const bf16x4 v = *(const bf16x4*)(A + m * 256 + lane * 4);
    const float4 wv = *(const float4*)(w4 + lane * 4);
    float sum = (float)v[0] * wv.x + (float)v[1] * wv.y + (float)v[2] * wv.z +
                (float)v[3] * wv.w;
#pragma unroll
    for (int off = 32; off > 0; off >>= 1) sum += __shfl_down(sum, off);
    if (lane == 0) out[m] = sum + b4[0];
}

// ---------------------------------------------------------------------------
extern "C" void kernel_launch(void* const* d_in, const int* in_sizes, int n_in,
                              void* d_out, int out_size, void* d_ws, size_t ws_size,
                              hipStream_t stream) {
    const float* numerical = (const float*)d_in[0];
    const int*   cat       = (const int*)d_in[1];
    const float* emb       = (const float*)d_in[2];
    const float* bw0 = (const float*)d_in[3];
    const float* bb0 = (const float*)d_in[4];
    const float* bw1 = (const float*)d_in[5];
    const float* bb1 = (const float*)d_in[6];
    const float* bw2 = (const float*)d_in[7];
    const float* bb2 = (const float*)d_in[8];
    const float* tw0 = (const float*)d_in[9];
    const float* tb0 = (const float*)d_in[10];
    const float* tw1 = (const float*)d_in[11];
    const float* tb1 = (const float*)d_in[12];
    const float* tw2 = (const float*)d_in[13];
    const float* tb2 = (const float*)d_in[14];
    const float* tw3 = (const float*)d_in[15];
    const float* tb3 = (const float*)d_in[16];
    const float* tw4 = (const float*)d_in[17];
    const float* tb4 = (const float*)d_in[18];
    float* out = (float*)d_out;

    char* ws = (char*)d_ws;
    size_t off = 0;
    auto alloc = [&](size_t bytes) {
        char* p = ws + off;
        off += (bytes + 255) & ~(size_t)255;
        return p;
    };
    bf16* wt0b = (bf16*)alloc((size_t)512 * 64 * 2);
    bf16* wt1b = (bf16*)alloc((size_t)256 * 512 * 2);
    bf16* wt2b = (bf16*)alloc((size_t)128 * 256 * 2);
    bf16* wt0t = (bf16*)alloc((size_t)1024 * 512 * 2);
    bf16* wt1t = (bf16*)alloc((size_t)1024 * 1024 * 2);
    bf16* wt2t = (bf16*)alloc((size_t)512 * 1024 * 2);
    bf16* wt3t = (bf16*)alloc((size_t)256 * 512 * 2);
    bf16* xpad = (bf16*)alloc((size_t)B_SZ * 64 * 2);
    bf16* h0   = (bf16*)alloc((size_t)B_SZ * 512 * 2);
    bf16* h1   = (bf16*)alloc((size_t)B_SZ * 256 * 2);
    bf16* bot  = (bf16*)alloc((size_t)B_SZ * 128 * 2);
    bf16* t0   = (bf16*)alloc((size_t)B_SZ * 1024 * 2);
    bf16* t1   = (bf16*)alloc((size_t)B_SZ * 1024 * 2);
    bf16* top_in = h0;
    bf16* t2 = t0;
    bf16* t3 = t1;

    // merged weight conversion
    CJobs js;
    js.j[0] = {bw0, wt0b, 16, 512, 64, 0};
    js.j[1] = {bw1, wt1b, 512, 256, 512, 128};
    js.j[2] = {bw2, wt2b, 256, 128, 256, 640};
    js.j[3] = {tw0, wt0t, 480, 1024, 512, 768};
    js.j[4] = {tw1, wt1t, 1024, 1024, 1024, 2816};
    js.j[5] = {tw2, wt2t, 1024, 512, 1024, 6912};
    js.j[6] = {tw3, wt3t, 512, 256, 512, 8960};
    convw_all<<<9472, 256, 0, stream>>>(js);

    make_xpad<<<(B_SZ * 64) / 256, 256, 0, stream>>>(numerical, xpad);

    // bottom MLP (128^2 kernel)
    gemm_bt<1><<<dim3(4, 256), 256, 0, stream>>>(xpad, wt0b, bb0, h0, B_SZ, 512, 64);
    gemm_bt<1><<<dim3(2, 256), 256, 0, stream>>>(h0, wt1b, bb1, h1, B_SZ, 256, 512);
    gemm_bt<1><<<dim3(1, 256), 256, 0, stream>>>(h1, wt2b, bb2, bot, B_SZ, 128, 256);

    interact_k<<<B_SZ / 4, 256, 0, stream>>>(emb, cat, bot, top_in);

    // top MLP: big 3 layers on the phase-split 256^2 kernel
    gemm256<1><<<dim3(4 * 128), 512, 0, stream>>>(top_in, wt0t, tb0, t0, B_SZ, 1024, 512, 4);
    gemm256<1><<<dim3(4 * 128), 512, 0, stream>>>(t0, wt1t, tb1, t1, B_SZ, 1024, 1024, 4);
    gemm256<1><<<dim3(2 * 128), 512, 0, stream>>>(t1, wt2t, tb2, t2, B_SZ, 512, 1024, 2);
    gemm_bt<1><<<dim3(2, 256), 256, 0, stream>>>(t2, wt3t, tb3, t3, B_SZ, 256, 512);

    gemv_final<<<B_SZ / 4, 256, 0, stream>>>(t3, tw4, tb4, out);
}

// Round 4
// 392.920 us; speedup vs baseline: 1.1400x; 1.0042x over previous
//
#include <hip/hip_runtime.h>

typedef __bf16 bf16;
typedef __bf16 bf16x4 __attribute__((ext_vector_type(4)));
typedef __bf16 bf16x8 __attribute__((ext_vector_type(8)));
typedef float f32x4 __attribute__((ext_vector_type(4)));

#define B_SZ 32768
#define T_CAT 26
#define V_SZ 100000
#define E_SZ 128

__device__ __forceinline__ void gload_lds16(const void* g, void* l) {
    __builtin_amdgcn_global_load_lds(
        (const __attribute__((address_space(1))) void*)g,
        (__attribute__((address_space(3))) void*)l, 16, 0, 0);
}

// ---------------------------------------------------------------------------
// Merged weight convert with LDS transpose: W (K x N fp32) -> Wt (N x Kp bf16),
// both global read and write coalesced. Each block does a 64(n) x 64(k) tile.
// ---------------------------------------------------------------------------
struct CJob { const float* W; bf16* Wt; int K, N, Kp, blk0, tk; };
struct CJobs { CJob j[7]; };

__global__ __launch_bounds__(256) void convw_all(CJobs js) {
    __shared__ bf16 tile[64][66];  // 66: 2-way bank aliasing on write (free)
    const int b = blockIdx.x;
    int ji = 0;
#pragma unroll
    for (int k = 1; k < 7; ++k)
        if (b >= js.j[k].blk0) ji = k;
    const CJob J = js.j[ji];
    const int local = b - J.blk0;
    const int tn = local / J.tk;       // tile along N
    const int tkk = local - tn * J.tk; // tile along Kp

    const int t = threadIdx.x;
    const int lx = t & 63;   // 0..63
    const int gy = t >> 6;   // 0..3

    // read phase: W[k][n], n coalesced; store transposed into LDS
#pragma unroll
    for (int kk = 0; kk < 16; ++kk) {
        const int k = tkk * 64 + kk * 4 + gy;
        const int n = tn * 64 + lx;
        const float v = (k < J.K) ? J.W[(long)k * J.N + n] : 0.0f;
        tile[lx][kk * 4 + gy] = (bf16)v;
    }
    __syncthreads();
    // write phase: Wt[n][k], k coalesced
#pragma unroll
    for (int nn = 0; nn < 16; ++nn) {
        const int nloc = nn * 4 + gy;
        const int n = tn * 64 + nloc;
        const int k = tkk * 64 + lx;
        J.Wt[(long)n * J.Kp + k] = tile[nloc][lx];
    }
}

// numerical (B x 13 fp32) -> xpad (B x 64 bf16), cols 13..63 zero
__global__ __launch_bounds__(256) void make_xpad(const float* __restrict__ num,
                                                 bf16* __restrict__ xp) {
    const int idx = blockIdx.x * 256 + threadIdx.x;  // B*64 threads
    const int b = idx >> 6, c = idx & 63;
    xp[idx] = (bf16)((c < 13) ? num[(long)b * 13 + c] : 0.0f);
}

// ---------------------------------------------------------------------------
// 128x128 tile GEMM (m97 structure) — small layers.
// ---------------------------------------------------------------------------
template <int RELU>
__global__ __launch_bounds__(256) void gemm_bt(const bf16* __restrict__ A,
                                               const bf16* __restrict__ Bt,
                                               const float* __restrict__ bias,
                                               bf16* __restrict__ C,
                                               int M, int N, int K) {
    __shared__ __align__(16) bf16 As[128 * 64];
    __shared__ __align__(16) bf16 Bs[128 * 64];
    const int t = threadIdx.x;
    const int lane = t & 63;
    const int w = t >> 6;
    const int wm = w >> 1, wn = w & 1;
    const long row0 = (long)blockIdx.y * 128;
    const long col0 = (long)blockIdx.x * 128;

    const int srow = t >> 3;
    const int scol = (t & 7) * 8;
    const bf16* Ag = A + (row0 + srow) * (long)K + scol;
    const bf16* Bg = Bt + (col0 + srow) * (long)K + scol;
    bf16* AsB = &As[w * 512];
    bf16* BsB = &Bs[w * 512];

    f32x4 acc[4][4] = {};

    for (int k0 = 0; k0 < K; k0 += 64) {
#pragma unroll
        for (int q = 0; q < 4; ++q) {
            gload_lds16(Ag + (long)q * 32 * K + k0, AsB + q * 2048);
            gload_lds16(Bg + (long)q * 32 * K + k0, BsB + q * 2048);
        }
        __syncthreads();
#pragma unroll
        for (int s = 0; s < 2; ++s) {
            bf16x8 af[4], bv[4];
#pragma unroll
            for (int i = 0; i < 4; ++i)
                af[i] = *(const bf16x8*)&As[(wm * 64 + i * 16 + (lane & 15)) * 64 +
                                            s * 32 + (lane >> 4) * 8];
#pragma unroll
            for (int j = 0; j < 4; ++j)
                bv[j] = *(const bf16x8*)&Bs[(wn * 64 + j * 16 + (lane & 15)) * 64 +
                                            s * 32 + (lane >> 4) * 8];
#pragma unroll
            for (int i = 0; i < 4; ++i)
#pragma unroll
                for (int j = 0; j < 4; ++j)
                    acc[i][j] = __builtin_amdgcn_mfma_f32_16x16x32_bf16(
                        af[i], bv[j], acc[i][j], 0, 0, 0);
        }
        __syncthreads();
    }

    const int r4 = (lane >> 4) * 4;
    const int cn = lane & 15;
#pragma unroll
    for (int j = 0; j < 4; ++j) {
        const long col = col0 + wn * 64 + j * 16 + cn;
        const float bj = bias[col];
#pragma unroll
        for (int i = 0; i < 4; ++i) {
#pragma unroll
            for (int r = 0; r < 4; ++r) {
                const long row = row0 + wm * 64 + i * 16 + r4 + r;
                float v = acc[i][j][r] + bj;
                if (RELU) v = v > 0.0f ? v : 0.0f;
                C[row * (long)N + col] = (bf16)v;
            }
        }
    }
}

// ---------------------------------------------------------------------------
// 256x256 tile GEMM, BK=32, 4-deep LDS ring, counted vmcnt, 2-phase per-tile
// interleave, setprio, 2-way-swizzled LDS. 8 waves (2x4), wave tile 128x64.
// Requires M%256==0, N%256==0, K%32==0, K/32 >= 4, grid%8 == 0.
// ---------------------------------------------------------------------------
template <int RELU>
__global__ __launch_bounds__(512, 2) void gemm256(const bf16* __restrict__ A,
                                                  const bf16* __restrict__ Bt,
                                                  const float* __restrict__ bias,
                                                  bf16* __restrict__ C,
                                                  int M, int N, int K, int nbx) {
    __shared__ __align__(16) bf16 lds[4 * 2 * 8192];
    const int t = threadIdx.x;
    const int lane = t & 63;
    const int w = t >> 6;
    const int wm = w >> 2, wn = w & 3;

    const int nwg = gridDim.x;
    const int qch = nwg >> 3;
    const int swz = ((int)blockIdx.x & 7) * qch + ((int)blockIdx.x >> 3);
    const int bx = swz % nbx, by = swz / nbx;
    const long row0 = (long)by * 256;
    const long col0 = (long)bx * 256;

    const int NT = K >> 5;

    const int lr = lane >> 2;
    const int dslot = lane & 3;
    const int lrow0 = (w * 2 + 0) * 16 + lr;
    const int lrow1 = (w * 2 + 1) * 16 + lr;
    const int sl0 = dslot ^ ((lrow0 >> 1) & 3);
    const int sl1 = dslot ^ ((lrow1 >> 1) & 3);
    const bf16* Ag0 = A + (row0 + lrow0) * (long)K + sl0 * 8;
    const bf16* Ag1 = A + (row0 + lrow1) * (long)K + sl1 * 8;
    const bf16* Bg0 = Bt + (col0 + lrow0) * (long)K + sl0 * 8;
    const bf16* Bg1 = Bt + (col0 + lrow1) * (long)K + sl1 * 8;
    const int ldsRow0 = (w * 2 + 0) * 512;
    const int ldsRow1 = (w * 2 + 1) * 512;

#define STAGE_A(buf, kt)                                                   \
    do {                                                                   \
        const int _k0 = (kt) << 5;                                         \
        gload_lds16(Ag0 + _k0, &lds[((buf) * 2 + 0) * 8192 + ldsRow0]);    \
        gload_lds16(Ag1 + _k0, &lds[((buf) * 2 + 0) * 8192 + ldsRow1]);    \
    } while (0)
#define STAGE_B(buf, kt)                                                   \
    do {                                                                   \
        const int _k0 = (kt) << 5;                                         \
        gload_lds16(Bg0 + _k0, &lds[((buf) * 2 + 1) * 8192 + ldsRow0]);    \
        gload_lds16(Bg1 + _k0, &lds[((buf) * 2 + 1) * 8192 + ldsRow1]);    \
    } while (0)

    const int cm = lane & 15;
    const int kc = lane >> 4;
    int aoff[8], boff[4];
#pragma unroll
    for (int i = 0; i < 8; ++i) {
        const int r = wm * 128 + i * 16 + cm;
        aoff[i] = r * 32 + (kc ^ ((r >> 1) & 3)) * 8;
    }
#pragma unroll
    for (int j = 0; j < 4; ++j) {
        const int n = wn * 64 + j * 16 + cm;
        boff[j] = n * 32 + (kc ^ ((n >> 1) & 3)) * 8;
    }

    f32x4 acc[8][4] = {};

    STAGE_A(0, 0); STAGE_B(0, 0);
    STAGE_A(1, 1); STAGE_B(1, 1);
    STAGE_A(2, 2); STAGE_B(2, 2);

    for (int tt = 0; tt < NT; ++tt) {
        const int rem = NT - 1 - tt;
        const int sb = (tt + 3) & 3;
        const int sk = tt + 3;

        if (rem >= 2)      asm volatile("s_waitcnt vmcnt(8)" ::: "memory");
        else if (rem == 1) asm volatile("s_waitcnt vmcnt(4)" ::: "memory");
        else               asm volatile("s_waitcnt vmcnt(0)" ::: "memory");
        __builtin_amdgcn_s_barrier();

        const bf16* Ab = &lds[((tt & 3) * 2 + 0) * 8192];
        const bf16* Bb = &lds[((tt & 3) * 2 + 1) * 8192];

        bf16x8 bfr[4], af[4];
#pragma unroll
        for (int j = 0; j < 4; ++j) bfr[j] = *(const bf16x8*)&Bb[boff[j]];
#pragma unroll
        for (int i = 0; i < 4; ++i) af[i] = *(const bf16x8*)&Ab[aoff[i]];
        if (rem >= 3) STAGE_A(sb, sk);
        __builtin_amdgcn_s_barrier();
        __builtin_amdgcn_s_setprio(1);
#pragma unroll
        for (int i = 0; i < 4; ++i)
#pragma unroll
            for (int j = 0; j < 4; ++j)
                acc[i][j] = __builtin_amdgcn_mfma_f32_16x16x32_bf16(
                    af[i], bfr[j], acc[i][j], 0, 0, 0);
        __builtin_amdgcn_s_setprio(0);

        bf16x8 af2[4];
#pragma unroll
        for (int i = 0; i < 4; ++i) af2[i] = *(const bf16x8*)&Ab[aoff[4 + i]];
        if (rem >= 3) STAGE_B(sb, sk);
        __builtin_amdgcn_s_barrier();
        __builtin_amdgcn_s_setprio(1);
#pragma unroll
        for (int i = 0; i < 4; ++i)
#pragma unroll
            for (int j = 0; j < 4; ++j)
                acc[4 + i][j] = __builtin_amdgcn_mfma_f32_16x16x32_bf16(
                    af2[i], bfr[j], acc[4 + i][j], 0, 0, 0);
        __builtin_amdgcn_s_setprio(0);
    }
#undef STAGE_A
#undef STAGE_B

    const int r4 = kc * 4;
#pragma unroll
    for (int j = 0; j < 4; ++j) {
        const long col = col0 + wn * 64 + j * 16 + cm;
        const float bj = bias[col];
#pragma unroll
        for (int i = 0; i < 8; ++i) {
#pragma unroll
            for (int r = 0; r < 4; ++r) {
                const long row = row0 + wm * 128 + i * 16 + r4 + r;
                float v = acc[i][j][r] + bj;
                if (RELU) v = v > 0.0f ? v : 0.0f;
                C[row * (long)N + col] = (bf16)v;
            }
        }
    }
}

// ---------------------------------------------------------------------------
// Fused embedding gather + pairwise interaction + top_in assembly.
// Fragments loaded DIRECTLY from global to registers (no feats LDS, no block
// barriers — each wave owns its gram/rowbuf slice; DS is in-order per wave,
// guarded by lgkmcnt(0) + sched_barrier).
// ---------------------------------------------------------------------------
__global__ __launch_bounds__(256) void interact_k(const float* __restrict__ emb,
                                                  const int* __restrict__ cat,
                                                  const bf16* __restrict__ bottom,
                                                  bf16* __restrict__ top_in) {
    __shared__ float gram[4][32 * 32];             // 16 KB
    __shared__ __align__(16) bf16 rowbuf[4][512];  // 4 KB
    const int t = threadIdx.x;
    const int lane = t & 63;
    const int w = t >> 6;
    const long s = (long)blockIdx.x * 4 + w;

    const int rl = lane & 15;  // row within 16-block
    const int kg = lane >> 4;  // k-group 0..3

    // fragment rows: i=0 -> r=rl (0..15), i=1 -> r=16+rl (16..31; >26 zero)
    bf16x8 f[2][4];
#pragma unroll
    for (int i = 0; i < 2; ++i) {
        const int r = i * 16 + rl;
        const float* rowp = nullptr;
        if (r >= 1 && r <= 26) {
            const int idx = cat[s * T_CAT + (r - 1)];
            rowp = emb + ((long)(r - 1) * V_SZ + idx) * E_SZ;
        }
#pragma unroll
        for (int ks = 0; ks < 4; ++ks) {
            const int c = ks * 32 + kg * 8;
            bf16x8 v = {};
            if (r == 0) {
                v = *(const bf16x8*)(bottom + s * 128 + c);
            } else if (r <= 26) {
                const float4 v0 = *(const float4*)(rowp + c);
                const float4 v1 = *(const float4*)(rowp + c + 4);
                v[0]=(bf16)v0.x; v[1]=(bf16)v0.y; v[2]=(bf16)v0.z; v[3]=(bf16)v0.w;
                v[4]=(bf16)v1.x; v[5]=(bf16)v1.y; v[6]=(bf16)v1.z; v[7]=(bf16)v1.w;
            }
            f[i][ks] = v;
        }
    }

    f32x4 a00 = {}, a01 = {}, a11 = {};
#pragma unroll
    for (int ks = 0; ks < 4; ++ks) {
        a00 = __builtin_amdgcn_mfma_f32_16x16x32_bf16(f[0][ks], f[0][ks], a00, 0, 0, 0);
        a01 = __builtin_amdgcn_mfma_f32_16x16x32_bf16(f[0][ks], f[1][ks], a01, 0, 0, 0);
        a11 = __builtin_amdgcn_mfma_f32_16x16x32_bf16(f[1][ks], f[1][ks], a11, 0, 0, 0);
    }

    const int r4 = kg * 4;
#pragma unroll
    for (int r = 0; r < 4; ++r) {
        gram[w][(r4 + r) * 32 + rl]           = a00[r];
        gram[w][(r4 + r) * 32 + 16 + rl]      = a01[r];
        gram[w][(16 + r4 + r) * 32 + 16 + rl] = a11[r];
    }
    asm volatile("s_waitcnt lgkmcnt(0)" ::: "memory");
    __builtin_amdgcn_sched_barrier(0);

    // assemble the 512-wide top_in row in LDS
    if (lane < 16)
        ((bf16x8*)&rowbuf[w][0])[lane] = ((const bf16x8*)(bottom + s * 128))[lane];
    for (int p = lane; p < 351; p += 64) {
        int i = 0, b = 0;
        while (b + (26 - i) <= p) { b += 26 - i; ++i; }
        const int j = p - b + i + 1;
        rowbuf[w][128 + p] = (bf16)gram[w][i * 32 + j];
    }
    if (lane >= 31) rowbuf[w][448 + lane] = (bf16)0.0f;  // cols 479..511
    asm volatile("s_waitcnt lgkmcnt(0)" ::: "memory");
    __builtin_amdgcn_sched_barrier(0);

    *(bf16x8*)(top_in + s * 512 + lane * 8) = *(const bf16x8*)&rowbuf[w][lane * 8];
}

// ---------------------------------------------------------------------------
// Final layer: out[m] = dot(act3[m] (bf16,256), tw4 (fp32)) + tb4.
// ---------------------------------------------------------------------------
__global__ __launch_bounds__(256) void gemv_final(const bf16* __restrict__ A,
                                                  const float* __restrict__ w4,
                                                  const float* __restrict__ b4,
                                                  float* __restrict__ out) {
    const int t = threadIdx.x;
    const int lane = t & 63;
    const int w = t >> 6;
    const long m = (long)blockIdx.x * 4 + w;
    const bf16x4 v = *(const bf16x4*)(A + m * 256 + lane * 4);
    const float4 wv = *(const float4*)(w4 + lane * 4);
    float sum = (float)v[0] * wv.x + (float)v[1] * wv.y + (float)v[2] * wv.z +
                (float)v[3] * wv.w;
#pragma unroll
    for (int off = 32; off > 0; off >>= 1) sum += __shfl_down(sum, off);
    if (lane == 0) out[m] = sum + b4[0];
}

// ---------------------------------------------------------------------------
extern "C" void kernel_launch(void* const* d_in, const int* in_sizes, int n_in,
                              void* d_out, int out_size, void* d_ws, size_t ws_size,
                              hipStream_t stream) {
    const float* numerical = (const float*)d_in[0];
    const int*   cat       = (const int*)d_in[1];
    const float* emb       = (const float*)d_in[2];
    const float* bw0 = (const float*)d_in[3];
    const float* bb0 = (const float*)d_in[4];
    const float* bw1 = (const float*)d_in[5];
    const float* bb1 = (const float*)d_in[6];
    const float* bw2 = (const float*)d_in[7];
    const float* bb2 = (const float*)d_in[8];
    const float* tw0 = (const float*)d_in[9];
    const float* tb0 = (const float*)d_in[10];
    const float* tw1 = (const float*)d_in[11];
    const float* tb1 = (const float*)d_in[12];
    const float* tw2 = (const float*)d_in[13];
    const float* tb2 = (const float*)d_in[14];
    const float* tw3 = (const float*)d_in[15];
    const float* tb3 = (const float*)d_in[16];
    const float* tw4 = (const float*)d_in[17];
    const float* tb4 = (const float*)d_in[18];
    float* out = (float*)d_out;

    char* ws = (char*)d_ws;
    size_t off = 0;
    auto alloc = [&](size_t bytes) {
        char* p = ws + off;
        off += (bytes + 255) & ~(size_t)255;
        return p;
    };
    bf16* wt0b = (bf16*)alloc((size_t)512 * 64 * 2);
    bf16* wt1b = (bf16*)alloc((size_t)256 * 512 * 2);
    bf16* wt2b = (bf16*)alloc((size_t)128 * 256 * 2);
    bf16* wt0t = (bf16*)alloc((size_t)1024 * 512 * 2);
    bf16* wt1t = (bf16*)alloc((size_t)1024 * 1024 * 2);
    bf16* wt2t = (bf16*)alloc((size_t)512 * 1024 * 2);
    bf16* wt3t = (bf16*)alloc((size_t)256 * 512 * 2);
    bf16* xpad = (bf16*)alloc((size_t)B_SZ * 64 * 2);
    bf16* h0   = (bf16*)alloc((size_t)B_SZ * 512 * 2);
    bf16* h1   = (bf16*)alloc((size_t)B_SZ * 256 * 2);
    bf16* bot  = (bf16*)alloc((size_t)B_SZ * 128 * 2);
    bf16* t0   = (bf16*)alloc((size_t)B_SZ * 1024 * 2);
    bf16* t1   = (bf16*)alloc((size_t)B_SZ * 1024 * 2);
    bf16* top_in = h0;
    bf16* t2 = t0;
    bf16* t3 = t1;

    // merged weight conversion (64x64 transpose tiles)
    CJobs js;
    js.j[0] = {bw0, wt0b, 16, 512, 64, 0, 1};       // 8 blocks
    js.j[1] = {bw1, wt1b, 512, 256, 512, 8, 8};     // 32
    js.j[2] = {bw2, wt2b, 256, 128, 256, 40, 4};    // 8
    js.j[3] = {tw0, wt0t, 480, 1024, 512, 48, 8};   // 128
    js.j[4] = {tw1, wt1t, 1024, 1024, 1024, 176, 16}; // 256
    js.j[5] = {tw2, wt2t, 1024, 512, 1024, 432, 16};  // 128
    js.j[6] = {tw3, wt3t, 512, 256, 512, 560, 8};     // 32
    convw_all<<<592, 256, 0, stream>>>(js);

    make_xpad<<<(B_SZ * 64) / 256, 256, 0, stream>>>(numerical, xpad);

    // bottom MLP
    gemm_bt<1><<<dim3(4, 256), 256, 0, stream>>>(xpad, wt0b, bb0, h0, B_SZ, 512, 64);
    gemm256<1><<<dim3(128), 512, 0, stream>>>(h0, wt1b, bb1, h1, B_SZ, 256, 512, 1);
    gemm_bt<1><<<dim3(1, 256), 256, 0, stream>>>(h1, wt2b, bb2, bot, B_SZ, 128, 256);

    interact_k<<<B_SZ / 4, 256, 0, stream>>>(emb, cat, bot, top_in);

    // top MLP
    gemm256<1><<<dim3(4 * 128), 512, 0, stream>>>(top_in, wt0t, tb0, t0, B_SZ, 1024, 512, 4);
    gemm256<1><<<dim3(4 * 128), 512, 0, stream>>>(t0, wt1t, tb1, t1, B_SZ, 1024, 1024, 4);
    gemm256<1><<<dim3(2 * 128), 512, 0, stream>>>(t1, wt2t, tb2, t2, B_SZ, 512, 1024, 2);
    gemm256<1><<<dim3(128), 512, 0, stream>>>(t2, wt3t, tb3, t3, B_SZ, 256, 512, 1);

    gemv_final<<<B_SZ / 4, 256, 0, stream>>>(t3, tw4, tb4, out);
}

// Round 5
// 388.550 us; speedup vs baseline: 1.1528x; 1.0112x over previous
//
#include <hip/hip_runtime.h>

typedef __bf16 bf16;
typedef __bf16 bf16x4 __attribute__((ext_vector_type(4)));
typedef __bf16 bf16x8 __attribute__((ext_vector_type(8)));
typedef float f32x4 __attribute__((ext_vector_type(4)));

#define B_SZ 32768
#define T_CAT 26
#define V_SZ 100000
#define E_SZ 128

__device__ __forceinline__ void gload_lds16(const void* g, void* l) {
    __builtin_amdgcn_global_load_lds(
        (const __attribute__((address_space(1))) void*)g,
        (__attribute__((address_space(3))) void*)l, 16, 0, 0);
}

// ---------------------------------------------------------------------------
// Merged weight convert with LDS transpose: W (K x N fp32) -> Wt (N x Kp bf16).
// ---------------------------------------------------------------------------
struct CJob { const float* W; bf16* Wt; int K, N, Kp, blk0, tk; };
struct CJobs { CJob j[7]; };

__global__ __launch_bounds__(256) void convw_all(CJobs js) {
    __shared__ bf16 tile[64][66];
    const int b = blockIdx.x;
    int ji = 0;
#pragma unroll
    for (int k = 1; k < 7; ++k)
        if (b >= js.j[k].blk0) ji = k;
    const CJob J = js.j[ji];
    const int local = b - J.blk0;
    const int tn = local / J.tk;
    const int tkk = local - tn * J.tk;

    const int t = threadIdx.x;
    const int lx = t & 63;
    const int gy = t >> 6;

#pragma unroll
    for (int kk = 0; kk < 16; ++kk) {
        const int k = tkk * 64 + kk * 4 + gy;
        const int n = tn * 64 + lx;
        const float v = (k < J.K) ? J.W[(long)k * J.N + n] : 0.0f;
        tile[lx][kk * 4 + gy] = (bf16)v;
    }
    __syncthreads();
#pragma unroll
    for (int nn = 0; nn < 16; ++nn) {
        const int nloc = nn * 4 + gy;
        const int n = tn * 64 + nloc;
        const int k = tkk * 64 + lx;
        J.Wt[(long)n * J.Kp + k] = tile[nloc][lx];
    }
}

// numerical (B x 13 fp32) -> xpad (B x 64 bf16)
__global__ __launch_bounds__(256) void make_xpad(const float* __restrict__ num,
                                                 bf16* __restrict__ xp) {
    const int idx = blockIdx.x * 256 + threadIdx.x;
    const int b = idx >> 6, c = idx & 63;
    xp[idx] = (bf16)((c < 13) ? num[(long)b * 13 + c] : 0.0f);
}

// ---------------------------------------------------------------------------
// 128x128 tile GEMM (m97 structure) — small layers.
// ---------------------------------------------------------------------------
template <int RELU>
__global__ __launch_bounds__(256) void gemm_bt(const bf16* __restrict__ A,
                                               const bf16* __restrict__ Bt,
                                               const float* __restrict__ bias,
                                               bf16* __restrict__ C,
                                               int M, int N, int K) {
    __shared__ __align__(16) bf16 As[128 * 64];
    __shared__ __align__(16) bf16 Bs[128 * 64];
    const int t = threadIdx.x;
    const int lane = t & 63;
    const int w = t >> 6;
    const int wm = w >> 1, wn = w & 1;
    const long row0 = (long)blockIdx.y * 128;
    const long col0 = (long)blockIdx.x * 128;

    const int srow = t >> 3;
    const int scol = (t & 7) * 8;
    const bf16* Ag = A + (row0 + srow) * (long)K + scol;
    const bf16* Bg = Bt + (col0 + srow) * (long)K + scol;
    bf16* AsB = &As[w * 512];
    bf16* BsB = &Bs[w * 512];

    f32x4 acc[4][4] = {};

    for (int k0 = 0; k0 < K; k0 += 64) {
#pragma unroll
        for (int q = 0; q < 4; ++q) {
            gload_lds16(Ag + (long)q * 32 * K + k0, AsB + q * 2048);
            gload_lds16(Bg + (long)q * 32 * K + k0, BsB + q * 2048);
        }
        __syncthreads();
#pragma unroll
        for (int s = 0; s < 2; ++s) {
            bf16x8 af[4], bv[4];
#pragma unroll
            for (int i = 0; i < 4; ++i)
                af[i] = *(const bf16x8*)&As[(wm * 64 + i * 16 + (lane & 15)) * 64 +
                                            s * 32 + (lane >> 4) * 8];
#pragma unroll
            for (int j = 0; j < 4; ++j)
                bv[j] = *(const bf16x8*)&Bs[(wn * 64 + j * 16 + (lane & 15)) * 64 +
                                            s * 32 + (lane >> 4) * 8];
#pragma unroll
            for (int i = 0; i < 4; ++i)
#pragma unroll
                for (int j = 0; j < 4; ++j)
                    acc[i][j] = __builtin_amdgcn_mfma_f32_16x16x32_bf16(
                        af[i], bv[j], acc[i][j], 0, 0, 0);
        }
        __syncthreads();
    }

    const int r4 = (lane >> 4) * 4;
    const int cn = lane & 15;
#pragma unroll
    for (int j = 0; j < 4; ++j) {
        const long col = col0 + wn * 64 + j * 16 + cn;
        const float bj = bias[col];
#pragma unroll
        for (int i = 0; i < 4; ++i) {
#pragma unroll
            for (int r = 0; r < 4; ++r) {
                const long row = row0 + wm * 64 + i * 16 + r4 + r;
                float v = acc[i][j][r] + bj;
                if (RELU) v = v > 0.0f ? v : 0.0f;
                C[row * (long)N + col] = (bf16)v;
            }
        }
    }
}

// ---------------------------------------------------------------------------
// 256x256 GEMM, BK=64, m201-style 8-phase schedule (2 K-tiles / unrolled iter).
// 2 LDS buffers x {A,B} x [kh][256][32] bf16 = 128 KiB. 8 waves (2x4).
// Per K-tile: 4 phases {ds_read ∥ stage half-tile -> barrier -> lgkmcnt(0) ->
// setprio(1) 16 MFMA setprio(0) -> barrier}; vmcnt(6) once per tile (never 0
// in main loop). Region lifetimes: Bkh0 freed after ph1, Akh0 after ph2,
// Bkh1 after ph3, Akh1 after ph4 -> stage Akh1(t+1)@ph1, Bkh0/Akh0/Bkh1(t+2)
// @ph2-4. vmcnt(6)@ph4 => all of tile t+1 landed (oldest-first).
// Requires M%256==0, N%256==0, K%128==0, K/64>=4, grid%8==0.
// ---------------------------------------------------------------------------
template <int RELU>
__global__ __launch_bounds__(512, 2) void gemm256(const bf16* __restrict__ A,
                                                  const bf16* __restrict__ Bt,
                                                  const float* __restrict__ bias,
                                                  bf16* __restrict__ C,
                                                  int M, int N, int K, int nbx) {
    // element layout: [buf(2)][mat(2): A,B][kh(2)][256 rows][32 k]
    __shared__ __align__(16) bf16 lds[65536];
    const int t = threadIdx.x;
    const int lane = t & 63;
    const int w = t >> 6;
    const int wm = w >> 2, wn = w & 3;

    const int nwg = gridDim.x;
    const int qch = nwg >> 3;
    const int swz = ((int)blockIdx.x & 7) * qch + ((int)blockIdx.x >> 3);
    const int bx = swz % nbx, by = swz / nbx;
    const long row0 = (long)by * 256;
    const long col0 = (long)bx * 256;

    const int NT = K >> 6;  // even, >= 4

    // staging: half-tile = [256 rows][32 k] contiguous; 2 instrs (q: rows 0-127 /
    // 128-255); thread t -> row q*128 + (t>>2), col16B (t&3). LDS dest linear.
    const int srow = t >> 2;
    const int scol = (t & 3) * 8;
    const bf16* Ag = A + (row0 + srow) * (long)K + scol;
    const bf16* Bg = Bt + (col0 + srow) * (long)K + scol;

#define STG(BUF, MAT, KH, KT)                                              \
    do {                                                                   \
        const bf16* _g = ((MAT) ? Bg : Ag) + (long)(KT)*64 + (KH)*32;      \
        bf16* _l = &lds[(BUF)*32768 + (MAT)*16384 + (KH)*8192 + w * 512];  \
        gload_lds16(_g, _l);                                               \
        gload_lds16(_g + 128 * (long)K, _l + 4096);                        \
    } while (0)

    // fragment bases (elements within a buffer)
    const int cm = lane & 15;
    const int kc = lane >> 4;
    const int abase = (wm * 128 + cm) * 32 + kc * 8;          // + i*512 + s*8192
    const int bbase = 16384 + (wn * 64 + cm) * 32 + kc * 8;   // + j*512 + s*8192

    bf16x8 bfr[4];
    f32x4 acc[8][4] = {};

#define PH(BUFB, S, IH, LOADB, STAGE, WAIT)                                   \
    do {                                                                      \
        if (LOADB) {                                                          \
            _Pragma("unroll") for (int j = 0; j < 4; ++j)                     \
                bfr[j] = *(const bf16x8*)&lds[(BUFB) + bbase + (S)*8192 + j*512]; \
        }                                                                     \
        bf16x8 af[4];                                                         \
        _Pragma("unroll") for (int i = 0; i < 4; ++i)                         \
            af[i] = *(const bf16x8*)&lds[(BUFB) + abase + (S)*8192 + ((IH)*4+i)*512]; \
        STAGE;                                                                \
        WAIT;                                                                 \
        asm volatile("" ::: "memory");                                       \
        __builtin_amdgcn_s_barrier();                                        \
        asm volatile("s_waitcnt lgkmcnt(0)" ::: "memory");                    \
        __builtin_amdgcn_s_setprio(1);                                       \
        _Pragma("unroll") for (int i = 0; i < 4; ++i)                         \
            _Pragma("unroll") for (int j = 0; j < 4; ++j)                     \
                acc[(IH)*4 + i][j] = __builtin_amdgcn_mfma_f32_16x16x32_bf16( \
                    af[i], bfr[j], acc[(IH)*4 + i][j], 0, 0, 0);              \
        __builtin_amdgcn_s_setprio(0);                                       \
        asm volatile("" ::: "memory");                                       \
        __builtin_amdgcn_s_barrier();                                        \
        asm volatile("" ::: "memory");                                       \
    } while (0)

#define TILE(BUFB, S1, S2, S3, S4, W4)          \
    PH(BUFB, 0, 0, 1, S1, ((void)0));           \
    PH(BUFB, 0, 1, 0, S2, ((void)0));           \
    PH(BUFB, 1, 0, 1, S3, ((void)0));           \
    PH(BUFB, 1, 1, 0, S4, W4)

#define VM6 asm volatile("s_waitcnt vmcnt(6)" ::: "memory")
#define VM0 asm volatile("s_waitcnt vmcnt(0)" ::: "memory")
#define NOP ((void)0)

    // prologue: tile0 (Bk0,Ak0,Bk1,Ak1) + tile1 (Bk0,Ak0,Bk1) = 14 loads
    STG(0, 1, 0, 0); STG(0, 0, 0, 0); STG(0, 1, 1, 0); STG(0, 0, 1, 0);
    STG(1, 1, 0, 1); STG(1, 0, 0, 1); STG(1, 1, 1, 1);
    VM6;  // tile 0 fully landed; 6 in flight
    __builtin_amdgcn_s_barrier();

    for (int tt = 0; tt + 3 < NT; tt += 2) {
        TILE(0,
             STG(1, 0, 1, tt + 1),   // Akh1(t+1) -> buf1
             STG(0, 1, 0, tt + 2),   // Bkh0(t+2) -> buf0 (freed end ph1)
             STG(0, 0, 0, tt + 2),   // Akh0(t+2)          (freed end ph2)
             STG(0, 1, 1, tt + 2),   // Bkh1(t+2)          (freed end ph3)
             VM6);
        TILE(32768,
             STG(0, 0, 1, tt + 2),
             STG(1, 1, 0, tt + 3),
             STG(1, 0, 0, tt + 3),
             STG(1, 1, 1, tt + 3),
             VM6);
    }
    // tail: tile NT-2 (buf0), tile NT-1 (buf1)
    TILE(0, STG(1, 0, 1, NT - 1), NOP, NOP, NOP, VM0);
    TILE(32768, NOP, NOP, NOP, NOP, NOP);

#undef STG
#undef PH
#undef TILE
#undef VM6
#undef VM0
#undef NOP

    // epilogue: D row = (lane>>4)*4 + reg, col = lane&15
    const int r4 = kc * 4;
#pragma unroll
    for (int j = 0; j < 4; ++j) {
        const long col = col0 + wn * 64 + j * 16 + cm;
        const float bj = bias[col];
#pragma unroll
        for (int i = 0; i < 8; ++i) {
#pragma unroll
            for (int r = 0; r < 4; ++r) {
                const long row = row0 + wm * 128 + i * 16 + r4 + r;
                float v = acc[i][j][r] + bj;
                if (RELU) v = v > 0.0f ? v : 0.0f;
                C[row * (long)N + col] = (bf16)v;
            }
        }
    }
}

// ---------------------------------------------------------------------------
// Fused embedding gather + pairwise interaction + top_in assembly.
// ---------------------------------------------------------------------------
__global__ __launch_bounds__(256) void interact_k(const float* __restrict__ emb,
                                                  const int* __restrict__ cat,
                                                  const bf16* __restrict__ bottom,
                                                  bf16* __restrict__ top_in) {
    __shared__ float gram[4][32 * 32];
    __shared__ __align__(16) bf16 rowbuf[4][512];
    const int t = threadIdx.x;
    const int lane = t & 63;
    const int w = t >> 6;
    const long s = (long)blockIdx.x * 4 + w;

    const int rl = lane & 15;
    const int kg = lane >> 4;

    bf16x8 f[2][4];
#pragma unroll
    for (int i = 0; i < 2; ++i) {
        const int r = i * 16 + rl;
        const float* rowp = nullptr;
        if (r >= 1 && r <= 26) {
            const int idx = cat[s * T_CAT + (r - 1)];
            rowp = emb + ((long)(r - 1) * V_SZ + idx) * E_SZ;
        }
#pragma unroll
        for (int ks = 0; ks < 4; ++ks) {
            const int c = ks * 32 + kg * 8;
            bf16x8 v = {};
            if (r == 0) {
                v = *(const bf16x8*)(bottom + s * 128 + c);
            } else if (r <= 26) {
                const float4 v0 = *(const float4*)(rowp + c);
                const float4 v1 = *(const float4*)(rowp + c + 4);
                v[0]=(bf16)v0.x; v[1]=(bf16)v0.y; v[2]=(bf16)v0.z; v[3]=(bf16)v0.w;
                v[4]=(bf16)v1.x; v[5]=(bf16)v1.y; v[6]=(bf16)v1.z; v[7]=(bf16)v1.w;
            }
            f[i][ks] = v;
        }
    }

    f32x4 a00 = {}, a01 = {}, a11 = {};
#pragma unroll
    for (int ks = 0; ks < 4; ++ks) {
        a00 = __builtin_amdgcn_mfma_f32_16x16x32_bf16(f[0][ks], f[0][ks], a00, 0, 0, 0);
        a01 = __builtin_amdgcn_mfma_f32_16x16x32_bf16(f[0][ks], f[1][ks], a01, 0, 0, 0);
        a11 = __builtin_amdgcn_mfma_f32_16x16x32_bf16(f[1][ks], f[1][ks], a11, 0, 0, 0);
    }

    const int r4 = kg * 4;
#pragma unroll
    for (int r = 0; r < 4; ++r) {
        gram[w][(r4 + r) * 32 + rl]           = a00[r];
        gram[w][(r4 + r) * 32 + 16 + rl]      = a01[r];
        gram[w][(16 + r4 + r) * 32 + 16 + rl] = a11[r];
    }
    asm volatile("s_waitcnt lgkmcnt(0)" ::: "memory");
    __builtin_amdgcn_sched_barrier(0);

    if (lane < 16)
        ((bf16x8*)&rowbuf[w][0])[lane] = ((const bf16x8*)(bottom + s * 128))[lane];
    for (int p = lane; p < 351; p += 64) {
        int i = 0, b = 0;
        while (b + (26 - i) <= p) { b += 26 - i; ++i; }
        const int j = p - b + i + 1;
        rowbuf[w][128 + p] = (bf16)gram[w][i * 32 + j];
    }
    if (lane >= 31) rowbuf[w][448 + lane] = (bf16)0.0f;
    asm volatile("s_waitcnt lgkmcnt(0)" ::: "memory");
    __builtin_amdgcn_sched_barrier(0);

    *(bf16x8*)(top_in + s * 512 + lane * 8) = *(const bf16x8*)&rowbuf[w][lane * 8];
}

// ---------------------------------------------------------------------------
// Final layer GEMV.
// ---------------------------------------------------------------------------
__global__ __launch_bounds__(256) void gemv_final(const bf16* __restrict__ A,
                                                  const float* __restrict__ w4,
                                                  const float* __restrict__ b4,
                                                  float* __restrict__ out) {
    const int t = threadIdx.x;
    const int lane = t & 63;
    const int w = t >> 6;
    const long m = (long)blockIdx.x * 4 + w;
    const bf16x4 v = *(const bf16x4*)(A + m * 256 + lane * 4);
    const float4 wv = *(const float4*)(w4 + lane * 4);
    float sum = (float)v[0] * wv.x + (float)v[1] * wv.y + (float)v[2] * wv.z +
                (float)v[3] * wv.w;
#pragma unroll
    for (int off = 32; off > 0; off >>= 1) sum += __shfl_down(sum, off);
    if (lane == 0) out[m] = sum + b4[0];
}

// ---------------------------------------------------------------------------
extern "C" void kernel_launch(void* const* d_in, const int* in_sizes, int n_in,
                              void* d_out, int out_size, void* d_ws, size_t ws_size,
                              hipStream_t stream) {
    const float* numerical = (const float*)d_in[0];
    const int*   cat       = (const int*)d_in[1];
    const float* emb       = (const float*)d_in[2];
    const float* bw0 = (const float*)d_in[3];
    const float* bb0 = (const float*)d_in[4];
    const float* bw1 = (const float*)d_in[5];
    const float* bb1 = (const float*)d_in[6];
    const float* bw2 = (const float*)d_in[7];
    const float* bb2 = (const float*)d_in[8];
    const float* tw0 = (const float*)d_in[9];
    const float* tb0 = (const float*)d_in[10];
    const float* tw1 = (const float*)d_in[11];
    const float* tb1 = (const float*)d_in[12];
    const float* tw2 = (const float*)d_in[13];
    const float* tb2 = (const float*)d_in[14];
    const float* tw3 = (const float*)d_in[15];
    const float* tb3 = (const float*)d_in[16];
    const float* tw4 = (const float*)d_in[17];
    const float* tb4 = (const float*)d_in[18];
    float* out = (float*)d_out;

    char* ws = (char*)d_ws;
    size_t off = 0;
    auto alloc = [&](size_t bytes) {
        char* p = ws + off;
        off += (bytes + 255) & ~(size_t)255;
        return p;
    };
    bf16* wt0b = (bf16*)alloc((size_t)512 * 64 * 2);
    bf16* wt1b = (bf16*)alloc((size_t)256 * 512 * 2);
    bf16* wt2b = (bf16*)alloc((size_t)128 * 256 * 2);
    bf16* wt0t = (bf16*)alloc((size_t)1024 * 512 * 2);
    bf16* wt1t = (bf16*)alloc((size_t)1024 * 1024 * 2);
    bf16* wt2t = (bf16*)alloc((size_t)512 * 1024 * 2);
    bf16* wt3t = (bf16*)alloc((size_t)256 * 512 * 2);
    bf16* xpad = (bf16*)alloc((size_t)B_SZ * 64 * 2);
    bf16* h0   = (bf16*)alloc((size_t)B_SZ * 512 * 2);
    bf16* h1   = (bf16*)alloc((size_t)B_SZ * 256 * 2);
    bf16* bot  = (bf16*)alloc((size_t)B_SZ * 128 * 2);
    bf16* t0   = (bf16*)alloc((size_t)B_SZ * 1024 * 2);
    bf16* t1   = (bf16*)alloc((size_t)B_SZ * 1024 * 2);
    bf16* top_in = h0;
    bf16* t2 = t0;
    bf16* t3 = t1;

    CJobs js;
    js.j[0] = {bw0, wt0b, 16, 512, 64, 0, 1};
    js.j[1] = {bw1, wt1b, 512, 256, 512, 8, 8};
    js.j[2] = {bw2, wt2b, 256, 128, 256, 40, 4};
    js.j[3] = {tw0, wt0t, 480, 1024, 512, 48, 8};
    js.j[4] = {tw1, wt1t, 1024, 1024, 1024, 176, 16};
    js.j[5] = {tw2, wt2t, 1024, 512, 1024, 432, 16};
    js.j[6] = {tw3, wt3t, 512, 256, 512, 560, 8};
    convw_all<<<592, 256, 0, stream>>>(js);

    make_xpad<<<(B_SZ * 64) / 256, 256, 0, stream>>>(numerical, xpad);

    // bottom MLP
    gemm_bt<1><<<dim3(4, 256), 256, 0, stream>>>(xpad, wt0b, bb0, h0, B_SZ, 512, 64);
    gemm256<1><<<dim3(128), 512, 0, stream>>>(h0, wt1b, bb1, h1, B_SZ, 256, 512, 1);
    gemm_bt<1><<<dim3(1, 256), 256, 0, stream>>>(h1, wt2b, bb2, bot, B_SZ, 128, 256);

    interact_k<<<B_SZ / 4, 256, 0, stream>>>(emb, cat, bot, top_in);

    // top MLP on the 8-phase 256^2 kernel
    gemm256<1><<<dim3(4 * 128), 512, 0, stream>>>(top_in, wt0t, tb0, t0, B_SZ, 1024, 512, 4);
    gemm256<1><<<dim3(4 * 128), 512, 0, stream>>>(t0, wt1t, tb1, t1, B_SZ, 1024, 1024, 4);
    gemm256<1><<<dim3(2 * 128), 512, 0, stream>>>(t1, wt2t, tb2, t2, B_SZ, 512, 1024, 2);
    gemm256<1><<<dim3(128), 512, 0, stream>>>(t2, wt3t, tb3, t3, B_SZ, 256, 512, 1);

    gemv_final<<<B_SZ / 4, 256, 0, stream>>>(t3, tw4, tb4, out);
}

// Round 6
// 339.595 us; speedup vs baseline: 1.3190x; 1.1442x over previous
//
#include <hip/hip_runtime.h>

typedef __bf16 bf16;
typedef __bf16 bf16x4 __attribute__((ext_vector_type(4)));
typedef __bf16 bf16x8 __attribute__((ext_vector_type(8)));
typedef float f32x4 __attribute__((ext_vector_type(4)));

#define B_SZ 32768
#define T_CAT 26
#define V_SZ 100000
#define E_SZ 128

__device__ __forceinline__ void gload_lds16(const void* g, void* l) {
    __builtin_amdgcn_global_load_lds(
        (const __attribute__((address_space(1))) void*)g,
        (__attribute__((address_space(3))) void*)l, 16, 0, 0);
}

// ---------------------------------------------------------------------------
// Merged weight convert with LDS transpose: W (K x N fp32) -> Wt (N x Kp bf16).
// ---------------------------------------------------------------------------
struct CJob { const float* W; bf16* Wt; int K, N, Kp, blk0, tk; };
struct CJobs { CJob j[7]; };

__global__ __launch_bounds__(256) void convw_all(CJobs js) {
    __shared__ bf16 tile[64][66];
    const int b = blockIdx.x;
    int ji = 0;
#pragma unroll
    for (int k = 1; k < 7; ++k)
        if (b >= js.j[k].blk0) ji = k;
    const CJob J = js.j[ji];
    const int local = b - J.blk0;
    const int tn = local / J.tk;
    const int tkk = local - tn * J.tk;

    const int t = threadIdx.x;
    const int lx = t & 63;
    const int gy = t >> 6;

#pragma unroll
    for (int kk = 0; kk < 16; ++kk) {
        const int k = tkk * 64 + kk * 4 + gy;
        const int n = tn * 64 + lx;
        const float v = (k < J.K) ? J.W[(long)k * J.N + n] : 0.0f;
        tile[lx][kk * 4 + gy] = (bf16)v;
    }
    __syncthreads();
#pragma unroll
    for (int nn = 0; nn < 16; ++nn) {
        const int nloc = nn * 4 + gy;
        const int n = tn * 64 + nloc;
        const int k = tkk * 64 + lx;
        J.Wt[(long)n * J.Kp + k] = tile[nloc][lx];
    }
}

// numerical (B x 13 fp32) -> xpad (B x 64 bf16)
__global__ __launch_bounds__(256) void make_xpad(const float* __restrict__ num,
                                                 bf16* __restrict__ xp) {
    const int idx = blockIdx.x * 256 + threadIdx.x;
    const int b = idx >> 6, c = idx & 63;
    xp[idx] = (bf16)((c < 13) ? num[(long)b * 13 + c] : 0.0f);
}

// ---------------------------------------------------------------------------
// 128x128 tile GEMM (m97 structure) — small layers (l0, l2).
// ---------------------------------------------------------------------------
template <int RELU>
__global__ __launch_bounds__(256) void gemm_bt(const bf16* __restrict__ A,
                                               const bf16* __restrict__ Bt,
                                               const float* __restrict__ bias,
                                               bf16* __restrict__ C,
                                               int M, int N, int K) {
    __shared__ __align__(16) bf16 As[128 * 64];
    __shared__ __align__(16) bf16 Bs[128 * 64];
    const int t = threadIdx.x;
    const int lane = t & 63;
    const int w = t >> 6;
    const int wm = w >> 1, wn = w & 1;
    const long row0 = (long)blockIdx.y * 128;
    const long col0 = (long)blockIdx.x * 128;

    const int srow = t >> 3;
    const int scol = (t & 7) * 8;
    const bf16* Ag = A + (row0 + srow) * (long)K + scol;
    const bf16* Bg = Bt + (col0 + srow) * (long)K + scol;
    bf16* AsB = &As[w * 512];
    bf16* BsB = &Bs[w * 512];

    f32x4 acc[4][4] = {};

    for (int k0 = 0; k0 < K; k0 += 64) {
#pragma unroll
        for (int q = 0; q < 4; ++q) {
            gload_lds16(Ag + (long)q * 32 * K + k0, AsB + q * 2048);
            gload_lds16(Bg + (long)q * 32 * K + k0, BsB + q * 2048);
        }
        __syncthreads();
#pragma unroll
        for (int s = 0; s < 2; ++s) {
            bf16x8 af[4], bv[4];
#pragma unroll
            for (int i = 0; i < 4; ++i)
                af[i] = *(const bf16x8*)&As[(wm * 64 + i * 16 + (lane & 15)) * 64 +
                                            s * 32 + (lane >> 4) * 8];
#pragma unroll
            for (int j = 0; j < 4; ++j)
                bv[j] = *(const bf16x8*)&Bs[(wn * 64 + j * 16 + (lane & 15)) * 64 +
                                            s * 32 + (lane >> 4) * 8];
#pragma unroll
            for (int i = 0; i < 4; ++i)
#pragma unroll
                for (int j = 0; j < 4; ++j)
                    acc[i][j] = __builtin_amdgcn_mfma_f32_16x16x32_bf16(
                        af[i], bv[j], acc[i][j], 0, 0, 0);
        }
        __syncthreads();
    }

    const int r4 = (lane >> 4) * 4;
    const int cn = lane & 15;
#pragma unroll
    for (int j = 0; j < 4; ++j) {
        const long col = col0 + wn * 64 + j * 16 + cn;
        const float bj = bias[col];
#pragma unroll
        for (int i = 0; i < 4; ++i) {
#pragma unroll
            for (int r = 0; r < 4; ++r) {
                const long row = row0 + wm * 64 + i * 16 + r4 + r;
                float v = acc[i][j][r] + bj;
                if (RELU) v = v > 0.0f ? v : 0.0f;
                C[row * (long)N + col] = (bf16)v;
            }
        }
    }
}

// ---------------------------------------------------------------------------
// 256x128 tile GEMM, BK=64, m97-style 2-barrier loop, compiler-scheduled.
// 8 waves (4m x 2n), wave tile 64x64, acc = 64 VGPR.
// __launch_bounds__(512,4) -> <=128 VGPR -> 2 blocks/CU (LDS 48KB x2 fits):
// cross-block overlap hides the barrier drain (m114 mechanism).
// LDS rows are 128B (64 bf16) -> XOR swizzle slot^=(row&7), applied on the
// pre-swizzled GLOBAL source (gload_lds dest stays linear) and on the frag
// read (rule #21, same involution both sides). Frag reads 2-way = free.
// Requires M%256==0, N%128==0, K%64==0, grid%8==0 (XCD swizzle).
// ---------------------------------------------------------------------------
template <int RELU>
__global__ __launch_bounds__(512, 4) void gemm_bt2(const bf16* __restrict__ A,
                                                   const bf16* __restrict__ Bt,
                                                   const float* __restrict__ bias,
                                                   bf16* __restrict__ C,
                                                   int M, int N, int K, int nbx) {
    __shared__ __align__(16) bf16 As[256 * 64];  // 32 KB
    __shared__ __align__(16) bf16 Bs[128 * 64];  // 16 KB
    const int t = threadIdx.x;
    const int lane = t & 63;
    const int w = t >> 6;            // 0..7
    const int wm = w >> 1, wn = w & 1;

    // bijective XCD swizzle: consecutive swz ids (same by-slab) share an XCD.
    const int nwg = gridDim.x;
    const int qch = nwg >> 3;
    const int swz = ((int)blockIdx.x & 7) * qch + ((int)blockIdx.x >> 3);
    const int bx = swz % nbx, by = swz / nbx;
    const long row0 = (long)by * 256;
    const long col0 = (long)bx * 128;

    // staging: per instr q, thread t -> row q*64 + (t>>3), 16B slot (t&7);
    // global col slot pre-swizzled by ^(row&7); LDS dest linear.
    const int srow = t >> 3;   // 0..63
    const int dslot = t & 7;
    const int gsl = dslot ^ (srow & 7);  // (q*64+srow)&7 == srow&7
    const bf16* Ag = A + (row0 + srow) * (long)K + gsl * 8;
    const bf16* Bg = Bt + (col0 + srow) * (long)K + gsl * 8;
    bf16* AsB = &As[w * 512];  // wave-uniform base; HW adds lane*16B
    bf16* BsB = &Bs[w * 512];

    const int cm = lane & 15;
    const int kc = lane >> 4;

    f32x4 acc[4][4] = {};

    for (int k0 = 0; k0 < K; k0 += 64) {
#pragma unroll
        for (int q = 0; q < 4; ++q)
            gload_lds16(Ag + (long)q * 64 * K + k0, AsB + q * 4096);
#pragma unroll
        for (int q = 0; q < 2; ++q)
            gload_lds16(Bg + (long)q * 64 * K + k0, BsB + q * 4096);
        __syncthreads();
#pragma unroll
        for (int s = 0; s < 2; ++s) {
            bf16x8 af[4], bv[4];
#pragma unroll
            for (int i = 0; i < 4; ++i) {
                const int r = wm * 64 + i * 16 + cm;
                af[i] = *(const bf16x8*)&As[r * 64 + (((s * 4 + kc) ^ (r & 7)) * 8)];
            }
#pragma unroll
            for (int j = 0; j < 4; ++j) {
                const int r = wn * 64 + j * 16 + cm;
                bv[j] = *(const bf16x8*)&Bs[r * 64 + (((s * 4 + kc) ^ (r & 7)) * 8)];
            }
#pragma unroll
            for (int i = 0; i < 4; ++i)
#pragma unroll
                for (int j = 0; j < 4; ++j)
                    acc[i][j] = __builtin_amdgcn_mfma_f32_16x16x32_bf16(
                        af[i], bv[j], acc[i][j], 0, 0, 0);
        }
        __syncthreads();
    }

    // epilogue: D row = (lane>>4)*4 + reg, col = lane&15
    const int r4 = kc * 4;
#pragma unroll
    for (int j = 0; j < 4; ++j) {
        const long col = col0 + wn * 64 + j * 16 + cm;
        const float bj = bias[col];
#pragma unroll
        for (int i = 0; i < 4; ++i) {
#pragma unroll
            for (int r = 0; r < 4; ++r) {
                const long row = row0 + wm * 64 + i * 16 + r4 + r;
                float v = acc[i][j][r] + bj;
                if (RELU) v = v > 0.0f ? v : 0.0f;
                C[row * (long)N + col] = (bf16)v;
            }
        }
    }
}

// ---------------------------------------------------------------------------
// Fused embedding gather + pairwise interaction + top_in assembly.
// ---------------------------------------------------------------------------
__global__ __launch_bounds__(256) void interact_k(const float* __restrict__ emb,
                                                  const int* __restrict__ cat,
                                                  const bf16* __restrict__ bottom,
                                                  bf16* __restrict__ top_in) {
    __shared__ float gram[4][32 * 32];
    __shared__ __align__(16) bf16 rowbuf[4][512];
    const int t = threadIdx.x;
    const int lane = t & 63;
    const int w = t >> 6;
    const long s = (long)blockIdx.x * 4 + w;

    const int rl = lane & 15;
    const int kg = lane >> 4;

    bf16x8 f[2][4];
#pragma unroll
    for (int i = 0; i < 2; ++i) {
        const int r = i * 16 + rl;
        const float* rowp = nullptr;
        if (r >= 1 && r <= 26) {
            const int idx = cat[s * T_CAT + (r - 1)];
            rowp = emb + ((long)(r - 1) * V_SZ + idx) * E_SZ;
        }
#pragma unroll
        for (int ks = 0; ks < 4; ++ks) {
            const int c = ks * 32 + kg * 8;
            bf16x8 v = {};
            if (r == 0) {
                v = *(const bf16x8*)(bottom + s * 128 + c);
            } else if (r <= 26) {
                const float4 v0 = *(const float4*)(rowp + c);
                const float4 v1 = *(const float4*)(rowp + c + 4);
                v[0]=(bf16)v0.x; v[1]=(bf16)v0.y; v[2]=(bf16)v0.z; v[3]=(bf16)v0.w;
                v[4]=(bf16)v1.x; v[5]=(bf16)v1.y; v[6]=(bf16)v1.z; v[7]=(bf16)v1.w;
            }
            f[i][ks] = v;
        }
    }

    f32x4 a00 = {}, a01 = {}, a11 = {};
#pragma unroll
    for (int ks = 0; ks < 4; ++ks) {
        a00 = __builtin_amdgcn_mfma_f32_16x16x32_bf16(f[0][ks], f[0][ks], a00, 0, 0, 0);
        a01 = __builtin_amdgcn_mfma_f32_16x16x32_bf16(f[0][ks], f[1][ks], a01, 0, 0, 0);
        a11 = __builtin_amdgcn_mfma_f32_16x16x32_bf16(f[1][ks], f[1][ks], a11, 0, 0, 0);
    }

    const int r4 = kg * 4;
#pragma unroll
    for (int r = 0; r < 4; ++r) {
        gram[w][(r4 + r) * 32 + rl]           = a00[r];
        gram[w][(r4 + r) * 32 + 16 + rl]      = a01[r];
        gram[w][(16 + r4 + r) * 32 + 16 + rl] = a11[r];
    }
    asm volatile("s_waitcnt lgkmcnt(0)" ::: "memory");
    __builtin_amdgcn_sched_barrier(0);

    if (lane < 16)
        ((bf16x8*)&rowbuf[w][0])[lane] = ((const bf16x8*)(bottom + s * 128))[lane];
    for (int p = lane; p < 351; p += 64) {
        int i = 0, b = 0;
        while (b + (26 - i) <= p) { b += 26 - i; ++i; }
        const int j = p - b + i + 1;
        rowbuf[w][128 + p] = (bf16)gram[w][i * 32 + j];
    }
    if (lane >= 31) rowbuf[w][448 + lane] = (bf16)0.0f;
    asm volatile("s_waitcnt lgkmcnt(0)" ::: "memory");
    __builtin_amdgcn_sched_barrier(0);

    *(bf16x8*)(top_in + s * 512 + lane * 8) = *(const bf16x8*)&rowbuf[w][lane * 8];
}

// ---------------------------------------------------------------------------
// Final layer GEMV.
// ---------------------------------------------------------------------------
__global__ __launch_bounds__(256) void gemv_final(const bf16* __restrict__ A,
                                                  const float* __restrict__ w4,
                                                  const float* __restrict__ b4,
                                                  float* __restrict__ out) {
    const int t = threadIdx.x;
    const int lane = t & 63;
    const int w = t >> 6;
    const long m = (long)blockIdx.x * 4 + w;
    const bf16x4 v = *(const bf16x4*)(A + m * 256 + lane * 4);
    const float4 wv = *(const float4*)(w4 + lane * 4);
    float sum = (float)v[0] * wv.x + (float)v[1] * wv.y + (float)v[2] * wv.z +
                (float)v[3] * wv.w;
#pragma unroll
    for (int off = 32; off > 0; off >>= 1) sum += __shfl_down(sum, off);
    if (lane == 0) out[m] = sum + b4[0];
}

// ---------------------------------------------------------------------------
extern "C" void kernel_launch(void* const* d_in, const int* in_sizes, int n_in,
                              void* d_out, int out_size, void* d_ws, size_t ws_size,
                              hipStream_t stream) {
    const float* numerical = (const float*)d_in[0];
    const int*   cat       = (const int*)d_in[1];
    const float* emb       = (const float*)d_in[2];
    const float* bw0 = (const float*)d_in[3];
    const float* bb0 = (const float*)d_in[4];
    const float* bw1 = (const float*)d_in[5];
    const float* bb1 = (const float*)d_in[6];
    const float* bw2 = (const float*)d_in[7];
    const float* bb2 = (const float*)d_in[8];
    const float* tw0 = (const float*)d_in[9];
    const float* tb0 = (const float*)d_in[10];
    const float* tw1 = (const float*)d_in[11];
    const float* tb1 = (const float*)d_in[12];
    const float* tw2 = (const float*)d_in[13];
    const float* tb2 = (const float*)d_in[14];
    const float* tw3 = (const float*)d_in[15];
    const float* tb3 = (const float*)d_in[16];
    const float* tw4 = (const float*)d_in[17];
    const float* tb4 = (const float*)d_in[18];
    float* out = (float*)d_out;

    char* ws = (char*)d_ws;
    size_t off = 0;
    auto alloc = [&](size_t bytes) {
        char* p = ws + off;
        off += (bytes + 255) & ~(size_t)255;
        return p;
    };
    bf16* wt0b = (bf16*)alloc((size_t)512 * 64 * 2);
    bf16* wt1b = (bf16*)alloc((size_t)256 * 512 * 2);
    bf16* wt2b = (bf16*)alloc((size_t)128 * 256 * 2);
    bf16* wt0t = (bf16*)alloc((size_t)1024 * 512 * 2);
    bf16* wt1t = (bf16*)alloc((size_t)1024 * 1024 * 2);
    bf16* wt2t = (bf16*)alloc((size_t)512 * 1024 * 2);
    bf16* wt3t = (bf16*)alloc((size_t)256 * 512 * 2);
    bf16* xpad = (bf16*)alloc((size_t)B_SZ * 64 * 2);
    bf16* h0   = (bf16*)alloc((size_t)B_SZ * 512 * 2);
    bf16* h1   = (bf16*)alloc((size_t)B_SZ * 256 * 2);
    bf16* bot  = (bf16*)alloc((size_t)B_SZ * 128 * 2);
    bf16* t0   = (bf16*)alloc((size_t)B_SZ * 1024 * 2);
    bf16* t1   = (bf16*)alloc((size_t)B_SZ * 1024 * 2);
    bf16* top_in = h0;
    bf16* t2 = t0;
    bf16* t3 = t1;

    CJobs js;
    js.j[0] = {bw0, wt0b, 16, 512, 64, 0, 1};
    js.j[1] = {bw1, wt1b, 512, 256, 512, 8, 8};
    js.j[2] = {bw2, wt2b, 256, 128, 256, 40, 4};
    js.j[3] = {tw0, wt0t, 480, 1024, 512, 48, 8};
    js.j[4] = {tw1, wt1t, 1024, 1024, 1024, 176, 16};
    js.j[5] = {tw2, wt2t, 1024, 512, 1024, 432, 16};
    js.j[6] = {tw3, wt3t, 512, 256, 512, 560, 8};
    convw_all<<<592, 256, 0, stream>>>(js);

    make_xpad<<<(B_SZ * 64) / 256, 256, 0, stream>>>(numerical, xpad);

    // bottom MLP
    gemm_bt<1><<<dim3(4, 256), 256, 0, stream>>>(xpad, wt0b, bb0, h0, B_SZ, 512, 64);
    gemm_bt2<1><<<dim3(256), 512, 0, stream>>>(h0, wt1b, bb1, h1, B_SZ, 256, 512, 2);
    gemm_bt<1><<<dim3(1, 256), 256, 0, stream>>>(h1, wt2b, bb2, bot, B_SZ, 128, 256);

    interact_k<<<B_SZ / 4, 256, 0, stream>>>(emb, cat, bot, top_in);

    // top MLP on the 256x128 2-block/CU kernel
    gemm_bt2<1><<<dim3(1024), 512, 0, stream>>>(top_in, wt0t, tb0, t0, B_SZ, 1024, 512, 8);
    gemm_bt2<1><<<dim3(1024), 512, 0, stream>>>(t0, wt1t, tb1, t1, B_SZ, 1024, 1024, 8);
    gemm_bt2<1><<<dim3(512), 512, 0, stream>>>(t1, wt2t, tb2, t2, B_SZ, 512, 1024, 4);
    gemm_bt2<1><<<dim3(256), 512, 0, stream>>>(t2, wt3t, tb3, t3, B_SZ, 256, 512, 2);

    gemv_final<<<B_SZ / 4, 256, 0, stream>>>(t3, tw4, tb4, out);
}